// Round 6
// baseline (208.354 us; speedup 1.0000x reference)
//
#include <hip/hip_runtime.h>
#include <math.h>

typedef float f32x4 __attribute__((ext_vector_type(4)));
typedef short s16x8 __attribute__((ext_vector_type(8)));
typedef unsigned short ushort_t;

namespace {
constexpr int kH  = 8;
constexpr int kD  = 64;
constexpr int kDM = 512;
constexpr int kB  = 2;
constexpr int kS  = 2048;
constexpr size_t kNE = (size_t)kB * kS * kDM;      // 2,097,152
constexpr size_t kNL = (size_t)kB * kH * kS;       // 32,768
}  // namespace

// Truncation split: x = hi + lo + eps, |eps| <= 2^-16 |x|
__device__ __forceinline__ void split_bf16(float x, ushort_t& hi, ushort_t& lo) {
  union { float f; unsigned u; } a; a.f = x;
  hi = (ushort_t)(a.u >> 16);
  union { unsigned u; float f; } hh; hh.u = a.u & 0xffff0000u;
  union { float f; unsigned u; } r; r.f = x - hh.f;
  lo = (ushort_t)(r.u >> 16);
}
// Round-to-nearest-even bf16
__device__ __forceinline__ ushort_t rne_bf16(float x) {
  union { float f; unsigned u; } a; a.f = x;
  const unsigned t = a.u + 0x7fffu + ((a.u >> 16) & 1u);
  return (ushort_t)(t >> 16);
}
__device__ __forceinline__ float bf_to_f(unsigned u16) {
  union { unsigned u; float f; } a; a.u = u16 << 16; return a.f;
}

// ---------------------------------------------------------------------------
// Kernel 1: Q/K/V projections via MFMA; W split in-register from fp32.
// grid (B*S/64, H, 4): z=0 -> k_hi [b,h,s,d]; z=1 -> vt_hi [b,h,d,key];
// z=2 -> Wo permuted split (blocks 0..127; rest idle); z=3 -> q_hi [b,h,s,d].
// ---------------------------------------------------------------------------
__global__ __launch_bounds__(256, 2)
void proj_kernel(const float* __restrict__ xk, const float* __restrict__ xv,
                 const float* __restrict__ xq,
                 const float* __restrict__ Wk, const float* __restrict__ bk,
                 const float* __restrict__ Wv, const float* __restrict__ bv,
                 const float* __restrict__ Wq, const float* __restrict__ bq,
                 const float* __restrict__ Wo,
                 ushort_t* __restrict__ wo_h, ushort_t* __restrict__ wo_l,
                 ushort_t* __restrict__ k_hi, ushort_t* __restrict__ vt_hi,
                 ushort_t* __restrict__ q_hi) {
  const int which = blockIdx.z;
  if (which == 2) {
    const int bid = blockIdx.y * 64 + blockIdx.x;
    if (bid < 128) {
      // Wo permuted split: woP[e][g] = Wo[e][(g&63)*8 + (g>>6)]
      const int gi = (bid * 256 + threadIdx.x) * 8;
      const int e  = gi >> 9;
      const int g0 = gi & 511;
      const int fbase = (g0 & 63) * 8 + (g0 >> 6);
      ushort_t h8[8], l8[8];
      #pragma unroll
      for (int j = 0; j < 8; ++j)
        split_bf16(Wo[(size_t)e * kDM + fbase + j * 8], h8[j], l8[j]);
      int4 hp, lp;
      hp.x = (int)((unsigned)h8[0] | ((unsigned)h8[1] << 16));
      hp.y = (int)((unsigned)h8[2] | ((unsigned)h8[3] << 16));
      hp.z = (int)((unsigned)h8[4] | ((unsigned)h8[5] << 16));
      hp.w = (int)((unsigned)h8[6] | ((unsigned)h8[7] << 16));
      lp.x = (int)((unsigned)l8[0] | ((unsigned)l8[1] << 16));
      lp.y = (int)((unsigned)l8[2] | ((unsigned)l8[3] << 16));
      lp.z = (int)((unsigned)l8[4] | ((unsigned)l8[5] << 16));
      lp.w = (int)((unsigned)l8[6] | ((unsigned)l8[7] << 16));
      *(int4*)&wo_h[(size_t)e * kDM + g0] = hp;
      *(int4*)&wo_l[(size_t)e * kDM + g0] = lp;
    }
    return;
  }

  __shared__ __align__(16) ushort_t Xh[64][72];
  __shared__ __align__(16) ushort_t Xl[64][72];
  const float* x    = (which == 1) ? xv : (which == 3 ? xq : xk);
  const float* W    = (which == 1) ? Wv : (which == 3 ? Wq : Wk);
  const float* bias = (which == 1) ? bv : (which == 3 ? bq : bk);
  const int h = blockIdx.y;
  const int t0g = blockIdx.x * 64;
  const int b = t0g >> 11, s0 = t0g & (kS - 1);
  const int tid  = threadIdx.x;
  const int w    = tid >> 6;
  const int lane = tid & 63;
  const int ln   = lane & 15;
  const int quad = lane >> 4;
  const size_t hb = ((size_t)b * kH + h) * (size_t)(kS * kD);

  #pragma unroll
  for (int cc = 0; cc < 4; ++cc) {
    const int id = tid + cc * 256;
    const int r = id >> 4, c = id & 15;
    const float4 v = *(const float4*)&x[((size_t)t0g + r) * kDM + h * kD + c * 4];
    ushort_t hh[4], ll[4];
    split_bf16(v.x, hh[0], ll[0]);
    split_bf16(v.y, hh[1], ll[1]);
    split_bf16(v.z, hh[2], ll[2]);
    split_bf16(v.w, hh[3], ll[3]);
    int2 hp, lp;
    hp.x = (int)((unsigned)hh[0] | ((unsigned)hh[1] << 16));
    hp.y = (int)((unsigned)hh[2] | ((unsigned)hh[3] << 16));
    lp.x = (int)((unsigned)ll[0] | ((unsigned)ll[1] << 16));
    lp.y = (int)((unsigned)ll[2] | ((unsigned)ll[3] << 16));
    *(int2*)&Xh[r][c * 4] = hp;
    *(int2*)&Xl[r][c * 4] = lp;
  }
  __syncthreads();

  f32x4 C[4];
  #pragma unroll
  for (int eb = 0; eb < 4; ++eb) C[eb] = (f32x4){0.f, 0.f, 0.f, 0.f};
  #pragma unroll
  for (int kc = 0; kc < 2; ++kc) {
    const s16x8 ah = *(const s16x8*)&Xh[w * 16 + ln][kc * 32 + quad * 8];
    const s16x8 al = *(const s16x8*)&Xl[w * 16 + ln][kc * 32 + quad * 8];
    #pragma unroll
    for (int eb = 0; eb < 4; ++eb) {
      const float* wp = &W[(size_t)(eb * 16 + ln) * kD + kc * 32 + quad * 8];
      const float4 w0 = *(const float4*)wp;
      const float4 w1 = *(const float4*)(wp + 4);
      const float ws[8] = {w0.x, w0.y, w0.z, w0.w, w1.x, w1.y, w1.z, w1.w};
      s16x8 bh, bl;
      #pragma unroll
      for (int j = 0; j < 8; ++j) {
        ushort_t hi, lo;
        split_bf16(ws[j], hi, lo);
        bh[j] = (short)hi; bl[j] = (short)lo;
      }
      C[eb] = __builtin_amdgcn_mfma_f32_16x16x32_bf16(ah, bh, C[eb], 0, 0, 0);
      C[eb] = __builtin_amdgcn_mfma_f32_16x16x32_bf16(ah, bl, C[eb], 0, 0, 0);
      C[eb] = __builtin_amdgcn_mfma_f32_16x16x32_bf16(al, bh, C[eb], 0, 0, 0);
    }
  }
  __syncthreads();

  if (which != 1) {
    ushort_t* dst = (which == 3) ? q_hi : k_hi;
    #pragma unroll
    for (int eb = 0; eb < 4; ++eb) {
      const float be = bias[eb * 16 + ln];
      #pragma unroll
      for (int r = 0; r < 4; ++r)
        Xh[w * 16 + quad * 4 + r][eb * 16 + ln] = rne_bf16(C[eb][r] + be);
    }
    __syncthreads();
    #pragma unroll
    for (int cc = 0; cc < 2; ++cc) {
      const int id = tid + cc * 256;
      const int r = id >> 3, c = id & 7;
      *(int4*)&dst[hb + (size_t)(s0 + r) * kD + c * 8] = *(int4*)&Xh[r][c * 8];
    }
  } else {
    #pragma unroll
    for (int eb = 0; eb < 4; ++eb) {
      const float be = bias[eb * 16 + ln];
      #pragma unroll
      for (int r = 0; r < 4; ++r)
        Xh[eb * 16 + ln][w * 16 + quad * 4 + r] = rne_bf16(C[eb][r] + be);
    }
    __syncthreads();
    #pragma unroll
    for (int cc = 0; cc < 2; ++cc) {
      const int id = tid + cc * 256;
      const int r = id >> 3, c = id & 7;
      *(int4*)&vt_hi[hb + (size_t)r * kS + s0 + c * 8] = *(int4*)&Xh[r][c * 8];
    }
  }
}

// ---------------------------------------------------------------------------
// Kernel 2: MFMA flash attention. Block 256 (4 waves), q-tile 128, wave owns
// 32 q-rows. Split-K x4: grid (S/128, H, B*4) = 1024 blocks, 3/CU (LDS).
// R5 verified structure (named-scalar T14 buffers, (256,3) cap) with
// KVBLK 64 -> 128: halves the barrier count (16 -> 8 per block) and
// tile-loop overheads. LDS 46.6 KB: Kh[128][72] + Vh[64][136] + Pb + Mz.
// Prefetch buffers 16 x int4 (+32 VGPR, ~116 total, under the ~170 cap).
// ---------------------------------------------------------------------------
__global__ __launch_bounds__(256, 3)
void attn_kernel(const ushort_t* __restrict__ q_hi,
                 const ushort_t* __restrict__ k_hi, const ushort_t* __restrict__ vt_hi,
                 const int* __restrict__ mask,
                 ushort_t* __restrict__ Opart, float* __restrict__ lws) {
  // smem: Kh[128][72] (18432B) | Vh[64][136] (17408B); QT[128][72] in epilogue.
  __shared__ __align__(16) ushort_t smem[128 * 72 + 64 * 136];
  __shared__ __align__(16) ushort_t Pbm[4 * 32 * 40];   // per-wave P (32q x 32k)
  __shared__ float Mz[128];
  ushort_t (*QT)[72]  = (ushort_t(*)[72])smem;
  ushort_t (*Kh)[72]  = (ushort_t(*)[72])smem;                  // [key][d]
  ushort_t (*Vh)[136] = (ushort_t(*)[136])(smem + 128 * 72);    // [d][key]
  ushort_t (*Pb)[32][40] = (ushort_t(*)[32][40])Pbm;

  const int tid  = threadIdx.x;
  const int w    = tid >> 6;          // wave 0..3
  const int lane = tid & 63;
  const int ln   = lane & 15;
  const int quad = lane >> 4;
  const int h    = blockIdx.y;
  const int b    = blockIdx.z >> 2;
  const int quarter = blockIdx.z & 3;
  const int q0   = blockIdx.x * 128;
  const size_t hb = ((size_t)b * kH + h) * (size_t)(kS * kD);

  // ---- Q fragments: direct from precomputed q_hi (bf16 [b,h,s,d]) ----
  s16x8 aqh[2][2];   // [group][db]
  #pragma unroll
  for (int g = 0; g < 2; ++g)
    #pragma unroll
    for (int db = 0; db < 2; ++db)
      aqh[g][db] = *(const s16x8*)
          &q_hi[hb + (size_t)(q0 + w * 32 + g * 16 + ln) * kD + db * 32 + quad * 8];

  f32x4 O[2][4];
  #pragma unroll
  for (int g = 0; g < 2; ++g)
    #pragma unroll
    for (int db = 0; db < 4; ++db) O[g][db] = (f32x4){0.f, 0.f, 0.f, 0.f};
  float rs[2][4] = {};

  // staging thread maps: K: 32 rows x 8 col-chunks; V: 16 d-rows x 16 key-chunks
  const int kr = tid >> 3, kc = (tid & 7) * 8;
  const int vr = tid >> 4, vc = (tid & 15) * 8;
  const ushort_t* gk0 = k_hi + hb + (size_t)kr * kD + kc;
  const ushort_t* gv0 = vt_hi + hb + (size_t)vr * kS + vc;
  const int kt0 = quarter * 4;        // tiles of 128 keys

// --- macros over NAMED register scalars (rule #20: no arrays/references) ---
#define PREFETCH_KV(TT, K0, K1, K2, K3, V0, V1, V2, V3, MM)                   \
  {                                                                           \
    K0 = *(const int4*)&gk0[((size_t)(TT) * 128) * kD];                       \
    K1 = *(const int4*)&gk0[((size_t)(TT) * 128 + 32) * kD];                  \
    K2 = *(const int4*)&gk0[((size_t)(TT) * 128 + 64) * kD];                  \
    K3 = *(const int4*)&gk0[((size_t)(TT) * 128 + 96) * kD];                  \
    V0 = *(const int4*)&gv0[(size_t)(TT) * 128];                              \
    V1 = *(const int4*)&gv0[16 * (size_t)kS + (size_t)(TT) * 128];            \
    V2 = *(const int4*)&gv0[32 * (size_t)kS + (size_t)(TT) * 128];            \
    V3 = *(const int4*)&gv0[48 * (size_t)kS + (size_t)(TT) * 128];            \
    if (tid < 128) MM = mask[(size_t)b * kS + (TT) * 128 + tid];              \
  }

#define STORE_KV(K0, K1, K2, K3, V0, V1, V2, V3, MM)                          \
  {                                                                           \
    *(int4*)&Kh[kr][kc]      = K0;                                            \
    *(int4*)&Kh[kr + 32][kc] = K1;                                            \
    *(int4*)&Kh[kr + 64][kc] = K2;                                            \
    *(int4*)&Kh[kr + 96][kc] = K3;                                            \
    *(int4*)&Vh[vr][vc]      = V0;                                            \
    *(int4*)&Vh[vr + 16][vc] = V1;                                            \
    *(int4*)&Vh[vr + 32][vc] = V2;                                            \
    *(int4*)&Vh[vr + 48][vc] = V3;                                            \
    if (tid < 128) Mz[tid] = (MM) ? 1.0f : 0.0f;                              \
  }

#define COMPUTE_TILE()                                                        \
  {                                                                           \
    _Pragma("unroll")                                                         \
    for (int h32 = 0; h32 < 4; ++h32) {                                       \
      f32x4 C[2][2];                                                          \
      _Pragma("unroll")                                                       \
      for (int g = 0; g < 2; ++g) {                                           \
        C[g][0] = (f32x4){0.f, 0.f, 0.f, 0.f};                                \
        C[g][1] = (f32x4){0.f, 0.f, 0.f, 0.f};                                \
      }                                                                       \
      __builtin_amdgcn_s_setprio(1);                                          \
      _Pragma("unroll")                                                       \
      for (int db = 0; db < 2; ++db) {                                        \
        const s16x8 bh0 = *(const s16x8*)&Kh[h32 * 32 + ln][db * 32 + quad * 8]; \
        const s16x8 bh1 = *(const s16x8*)&Kh[h32 * 32 + 16 + ln][db * 32 + quad * 8]; \
        _Pragma("unroll")                                                     \
        for (int g = 0; g < 2; ++g) {                                         \
          C[g][0] = __builtin_amdgcn_mfma_f32_16x16x32_bf16(aqh[g][db], bh0, C[g][0], 0, 0, 0); \
          C[g][1] = __builtin_amdgcn_mfma_f32_16x16x32_bf16(aqh[g][db], bh1, C[g][1], 0, 0, 0); \
        }                                                                     \
      }                                                                       \
      __builtin_amdgcn_s_setprio(0);                                          \
      _Pragma("unroll")                                                       \
      for (int g = 0; g < 2; ++g) {                                           \
        _Pragma("unroll")                                                     \
        for (int kb = 0; kb < 2; ++kb) {                                      \
          const float mz = Mz[h32 * 32 + kb * 16 + ln];                       \
          _Pragma("unroll")                                                   \
          for (int r = 0; r < 4; ++r) {                                       \
            const float p = mz * __expf(0.25f * C[g][kb][r]);                 \
            union { float f; unsigned u; } pa; pa.f = p;                      \
            const unsigned tt = pa.u + 0x7fffu + ((pa.u >> 16) & 1u);         \
            Pb[w][g * 16 + quad * 4 + r][kb * 16 + ln] = (ushort_t)(tt >> 16); \
            union { unsigned u; float f; } pr; pr.u = tt & 0xffff0000u;       \
            rs[g][r] += pr.f;                                                 \
          }                                                                   \
        }                                                                     \
      }                                                                       \
      {                                                                       \
        const s16x8 ph0 = *(const s16x8*)&Pb[w][ln][quad * 8];                \
        const s16x8 ph1 = *(const s16x8*)&Pb[w][16 + ln][quad * 8];           \
        __builtin_amdgcn_s_setprio(1);                                        \
        _Pragma("unroll")                                                     \
        for (int db = 0; db < 4; ++db) {                                      \
          const s16x8 vh = *(const s16x8*)&Vh[db * 16 + ln][h32 * 32 + quad * 8]; \
          O[0][db] = __builtin_amdgcn_mfma_f32_16x16x32_bf16(ph0, vh, O[0][db], 0, 0, 0); \
          O[1][db] = __builtin_amdgcn_mfma_f32_16x16x32_bf16(ph1, vh, O[1][db], 0, 0, 0); \
        }                                                                     \
        __builtin_amdgcn_s_setprio(0);                                        \
      }                                                                       \
    }                                                                         \
  }

  int4 kA0, kA1, kA2, kA3, vA0, vA1, vA2, vA3;
  int4 kB0, kB1, kB2, kB3, vB0, vB1, vB2, vB3;
  int mA = 0, mB = 0;
  PREFETCH_KV(kt0, kA0, kA1, kA2, kA3, vA0, vA1, vA2, vA3, mA);

  for (int i = 0; i < 2; ++i) {
    const int base = kt0 + i * 2;
    if (i) __syncthreads();                 // prev tile's LDS reads done
    PREFETCH_KV(base + 1, kB0, kB1, kB2, kB3, vB0, vB1, vB2, vB3, mB);
    STORE_KV(kA0, kA1, kA2, kA3, vA0, vA1, vA2, vA3, mA);
    __syncthreads();
    COMPUTE_TILE();
    __syncthreads();                        // tile A's LDS reads done
    if (i < 1) PREFETCH_KV(base + 2, kA0, kA1, kA2, kA3, vA0, vA1, vA2, vA3, mA);
    STORE_KV(kB0, kB1, kB2, kB3, vB0, vB1, vB2, vB3, mB);
    __syncthreads();
    COMPUTE_TILE();
  }

#undef PREFETCH_KV
#undef STORE_KV
#undef COMPUTE_TILE

  // ---- l partials: 16-lane group reduce, plain store ----
  #pragma unroll
  for (int m = 1; m < 16; m <<= 1) {
    #pragma unroll
    for (int g = 0; g < 2; ++g)
      #pragma unroll
      for (int r = 0; r < 4; ++r) rs[g][r] += __shfl_xor(rs[g][r], m);
  }
  if (ln == 0) {
    #pragma unroll
    for (int g = 0; g < 2; ++g) {
      float* lp = lws + (size_t)quarter * kNL + ((size_t)b * kH + h) * kS +
                  q0 + w * 32 + g * 16 + quad * 4;
      #pragma unroll
      for (int r = 0; r < 4; ++r) lp[r] = rs[g][r];
    }
  }

  // ---- O partials: RNE bf16, LDS repack, coalesced stores ----
  __syncthreads();   // Kh/Vh dead
  #pragma unroll
  for (int g = 0; g < 2; ++g)
    #pragma unroll
    for (int db = 0; db < 4; ++db)
      #pragma unroll
      for (int r = 0; r < 4; ++r)
        QT[w * 32 + g * 16 + quad * 4 + r][db * 16 + ln] = rne_bf16(O[g][db][r]);
  __syncthreads();
  ushort_t* op = Opart + (size_t)quarter * kNE;
  #pragma unroll
  for (int cc = 0; cc < 4; ++cc) {
    const int id = tid + cc * 256;
    const int r = id >> 3, c = id & 7;
    *(int4*)&op[((size_t)b * kS + q0 + r) * kDM + h * kD + c * 8] = *(int4*)&QT[r][c * 8];
  }
}

// ---------------------------------------------------------------------------
// Kernel 3: MFMA output projection with fused split-K combine.
// t-tile 32, e-tile 128, k-step 32 -> Opart re-read factor 4.
// grid (B*S/32, DM/128), block 256 (4 waves: tsub = w&1, esub = w>>1).
// T14 register prefetch of next iteration's 8 global loads (kept from R0;
// cap here is 256 regs at (256,2) so no spill risk).
// ---------------------------------------------------------------------------
__global__ __launch_bounds__(256, 2)
void out_proj_kernel(const ushort_t* __restrict__ Opart, const float* __restrict__ lws,
                     const ushort_t* __restrict__ wh, const ushort_t* __restrict__ wl,
                     const float* __restrict__ bo, float* __restrict__ out) {
  __shared__ __align__(16) ushort_t Ah[32][40];
  __shared__ __align__(16) ushort_t Al[32][40];
  __shared__ __align__(16) ushort_t Bh[128][40];
  __shared__ __align__(16) ushort_t Bl[128][40];
  __shared__ float linv[kH][32];
  const int t0 = blockIdx.x * 32;
  const int e0 = blockIdx.y * 128;
  const int b  = t0 >> 11;
  const int s0 = t0 & (kS - 1);
  const int tid  = threadIdx.x;
  const int w    = tid >> 6;
  const int lane = tid & 63;
  const int ln   = lane & 15;
  const int quad = lane >> 4;
  const int tsub = w & 1;
  const int esub = w >> 1;

  {  // 8 heads x 32 rows: one l-sum per thread
    const int hh = tid >> 5, r = tid & 31;
    const size_t base = ((size_t)b * kH + hh) * kS + s0 + r;
    linv[hh][r] = 1.0f / (lws[base] + lws[kNL + base] +
                          lws[2 * kNL + base] + lws[3 * kNL + base]);
  }

  // per-thread staging coordinates (constant across the k-loop)
  const int ra  = tid >> 3, ca = (tid & 7) * 4;                   // A row/col4
  const int rb0 = tid >> 2, cb0 = (tid & 3) * 8;                  // B chunk 0
  const int rb1 = (tid + 256) >> 2, cb1 = ((tid + 256) & 3) * 8;  // B chunk 1
  const ushort_t* ap  = &Opart[(size_t)(t0 + ra) * kDM + ca];
  const ushort_t* bhp0 = &wh[(size_t)(e0 + rb0) * kDM + cb0];
  const ushort_t* blp0 = &wl[(size_t)(e0 + rb0) * kDM + cb0];
  const ushort_t* bhp1 = &wh[(size_t)(e0 + rb1) * kDM + cb1];
  const ushort_t* blp1 = &wl[(size_t)(e0 + rb1) * kDM + cb1];

  f32x4 C[4];
  #pragma unroll
  for (int eb = 0; eb < 4; ++eb) C[eb] = (f32x4){0.f, 0.f, 0.f, 0.f};

  // ---- prefetch k0 = 0 ----
  int2 pa0 = *(const int2*)(ap);
  int2 pa1 = *(const int2*)(ap + kNE);
  int2 pa2 = *(const int2*)(ap + 2 * kNE);
  int2 pa3 = *(const int2*)(ap + 3 * kNE);
  int4 pb0h = *(const int4*)(bhp0);
  int4 pb0l = *(const int4*)(blp0);
  int4 pb1h = *(const int4*)(bhp1);
  int4 pb1l = *(const int4*)(blp1);

  for (int k0 = 0; k0 < kDM; k0 += 32) {
    __syncthreads();
    // ---- consume prefetched A: sum 4 bf16 partials -> /l -> split ----
    {
      const int hh = k0 >> 6;
      float a0 = bf_to_f((unsigned)pa0.x & 0xffffu);
      float a1 = bf_to_f((unsigned)pa0.x >> 16);
      float a2 = bf_to_f((unsigned)pa0.y & 0xffffu);
      float a3 = bf_to_f((unsigned)pa0.y >> 16);
      a0 += bf_to_f((unsigned)pa1.x & 0xffffu);
      a1 += bf_to_f((unsigned)pa1.x >> 16);
      a2 += bf_to_f((unsigned)pa1.y & 0xffffu);
      a3 += bf_to_f((unsigned)pa1.y >> 16);
      a0 += bf_to_f((unsigned)pa2.x & 0xffffu);
      a1 += bf_to_f((unsigned)pa2.x >> 16);
      a2 += bf_to_f((unsigned)pa2.y & 0xffffu);
      a3 += bf_to_f((unsigned)pa2.y >> 16);
      a0 += bf_to_f((unsigned)pa3.x & 0xffffu);
      a1 += bf_to_f((unsigned)pa3.x >> 16);
      a2 += bf_to_f((unsigned)pa3.y & 0xffffu);
      a3 += bf_to_f((unsigned)pa3.y >> 16);
      const float li = linv[hh][ra];
      a0 *= li; a1 *= li; a2 *= li; a3 *= li;
      ushort_t h4[4], l4[4];
      split_bf16(a0, h4[0], l4[0]);
      split_bf16(a1, h4[1], l4[1]);
      split_bf16(a2, h4[2], l4[2]);
      split_bf16(a3, h4[3], l4[3]);
      int2 hp, lp;
      hp.x = (int)((unsigned)h4[0] | ((unsigned)h4[1] << 16));
      hp.y = (int)((unsigned)h4[2] | ((unsigned)h4[3] << 16));
      lp.x = (int)((unsigned)l4[0] | ((unsigned)l4[1] << 16));
      lp.y = (int)((unsigned)l4[2] | ((unsigned)l4[3] << 16));
      *(int2*)&Ah[ra][ca] = hp;
      *(int2*)&Al[ra][ca] = lp;
    }
    // ---- consume prefetched B ----
    *(int4*)&Bh[rb0][cb0] = pb0h;
    *(int4*)&Bl[rb0][cb0] = pb0l;
    *(int4*)&Bh[rb1][cb1] = pb1h;
    *(int4*)&Bl[rb1][cb1] = pb1l;
    // ---- issue next iteration's loads (latency hides under MFMA) ----
    if (k0 + 32 < kDM) {
      const int kn = k0 + 32;
      pa0 = *(const int2*)(ap + kn);
      pa1 = *(const int2*)(ap + kNE + kn);
      pa2 = *(const int2*)(ap + 2 * kNE + kn);
      pa3 = *(const int2*)(ap + 3 * kNE + kn);
      pb0h = *(const int4*)(bhp0 + kn);
      pb0l = *(const int4*)(blp0 + kn);
      pb1h = *(const int4*)(bhp1 + kn);
      pb1l = *(const int4*)(blp1 + kn);
    }
    __syncthreads();
    const s16x8 ah = *(const s16x8*)&Ah[tsub * 16 + ln][quad * 8];
    const s16x8 al = *(const s16x8*)&Al[tsub * 16 + ln][quad * 8];
    #pragma unroll
    for (int eb = 0; eb < 4; ++eb) {
      const s16x8 bh = *(const s16x8*)&Bh[esub * 64 + eb * 16 + ln][quad * 8];
      const s16x8 bl = *(const s16x8*)&Bl[esub * 64 + eb * 16 + ln][quad * 8];
      C[eb] = __builtin_amdgcn_mfma_f32_16x16x32_bf16(ah, bh, C[eb], 0, 0, 0);
      C[eb] = __builtin_amdgcn_mfma_f32_16x16x32_bf16(ah, bl, C[eb], 0, 0, 0);
      C[eb] = __builtin_amdgcn_mfma_f32_16x16x32_bf16(al, bh, C[eb], 0, 0, 0);
    }
  }

  #pragma unroll
  for (int eb = 0; eb < 4; ++eb) {
    const int e = e0 + esub * 64 + eb * 16 + ln;
    const float be = bo[e];
    #pragma unroll
    for (int r = 0; r < 4; ++r) {
      const int t = t0 + tsub * 16 + quad * 4 + r;
      out[(size_t)t * kDM + e] = C[eb][r] + be;
    }
  }
}

// ---------------------------------------------------------------------------
extern "C" void kernel_launch(void* const* d_in, const int* in_sizes, int n_in,
                              void* d_out, int out_size, void* d_ws, size_t ws_size,
                              hipStream_t stream) {
  const float* query = (const float*)d_in[0];
  const float* key   = (const float*)d_in[1];
  const float* value = (const float*)d_in[2];
  const float* Wq = (const float*)d_in[3];
  const float* bq = (const float*)d_in[4];
  const float* Wk = (const float*)d_in[5];
  const float* bk = (const float*)d_in[6];
  const float* Wv = (const float*)d_in[7];
  const float* bv = (const float*)d_in[8];
  const float* Wo = (const float*)d_in[9];
  const float* bo = (const float*)d_in[10];
  const int* mask = (const int*)d_in[11];
  float* out = (float*)d_out;

  ushort_t* k_hi  = (ushort_t*)d_ws;            // 4MB
  ushort_t* vt_hi = k_hi + kNE;                 // 4MB
  ushort_t* wo_h  = vt_hi + kNE;                // 512KB
  ushort_t* wo_l  = wo_h + (size_t)kDM * kDM;   // 512KB
  ushort_t* Opart = wo_l + (size_t)kDM * kDM;   // 16MB (4 quarters, bf16)
  float*    lws   = (float*)(Opart + 4 * kNE);  // 512KB (4 quarters)
  ushort_t* q_hi  = (ushort_t*)(lws + 4 * kNL); // 4MB   (total ~29.5 MB)

  proj_kernel<<<dim3(kB * kS / 64, kH, 4), 256, 0, stream>>>(
      key, value, query, Wk, bk, Wv, bv, Wq, bq, Wo, wo_h, wo_l, k_hi, vt_hi, q_hi);
  attn_kernel<<<dim3(kS / 128, kH, kB * 4), 256, 0, stream>>>(
      q_hi, k_hi, vt_hi, mask, Opart, lws);
  out_proj_kernel<<<dim3(kB * kS / 32, kDM / 128), 256, 0, stream>>>(
      Opart, lws, wo_h, wo_l, bo, out);
}

// Round 7
// 178.451 us; speedup vs baseline: 1.1676x; 1.1676x over previous
//
#include <hip/hip_runtime.h>
#include <math.h>

typedef float f32x4 __attribute__((ext_vector_type(4)));
typedef short s16x8 __attribute__((ext_vector_type(8)));
typedef unsigned short ushort_t;

namespace {
constexpr int kH  = 8;
constexpr int kD  = 64;
constexpr int kDM = 512;
constexpr int kB  = 2;
constexpr int kS  = 2048;
constexpr size_t kNE = (size_t)kB * kS * kDM;      // 2,097,152
constexpr size_t kNL = (size_t)kB * kH * kS;       // 32,768
}  // namespace

// Truncation split: x = hi + lo + eps, |eps| <= 2^-16 |x|
__device__ __forceinline__ void split_bf16(float x, ushort_t& hi, ushort_t& lo) {
  union { float f; unsigned u; } a; a.f = x;
  hi = (ushort_t)(a.u >> 16);
  union { unsigned u; float f; } hh; hh.u = a.u & 0xffff0000u;
  union { float f; unsigned u; } r; r.f = x - hh.f;
  lo = (ushort_t)(r.u >> 16);
}
// Round-to-nearest-even bf16
__device__ __forceinline__ ushort_t rne_bf16(float x) {
  union { float f; unsigned u; } a; a.f = x;
  const unsigned t = a.u + 0x7fffu + ((a.u >> 16) & 1u);
  return (ushort_t)(t >> 16);
}
__device__ __forceinline__ float bf_to_f(unsigned u16) {
  union { unsigned u; float f; } a; a.u = u16 << 16; return a.f;
}

// ---------------------------------------------------------------------------
// Kernel 1: Q/K/V projections via MFMA; W split in-register from fp32.
// grid (B*S/64, H, 4): z=0 -> k_hi [b,h,s,d]; z=1 -> vt_hi [b,h,d,key];
// z=2 -> Wo permuted split (blocks 0..127; rest idle); z=3 -> q_hi [b,h,s,d].
// q_hi is PRE-SCALED by 0.25 (the softmax scale): power-of-2, so the bf16
// split is bitwise-equivalent and attn can use __expf(S) with no mul.
// ---------------------------------------------------------------------------
__global__ __launch_bounds__(256, 2)
void proj_kernel(const float* __restrict__ xk, const float* __restrict__ xv,
                 const float* __restrict__ xq,
                 const float* __restrict__ Wk, const float* __restrict__ bk,
                 const float* __restrict__ Wv, const float* __restrict__ bv,
                 const float* __restrict__ Wq, const float* __restrict__ bq,
                 const float* __restrict__ Wo,
                 ushort_t* __restrict__ wo_h, ushort_t* __restrict__ wo_l,
                 ushort_t* __restrict__ k_hi, ushort_t* __restrict__ vt_hi,
                 ushort_t* __restrict__ q_hi) {
  const int which = blockIdx.z;
  if (which == 2) {
    const int bid = blockIdx.y * 64 + blockIdx.x;
    if (bid < 128) {
      // Wo permuted split: woP[e][g] = Wo[e][(g&63)*8 + (g>>6)]
      const int gi = (bid * 256 + threadIdx.x) * 8;
      const int e  = gi >> 9;
      const int g0 = gi & 511;
      const int fbase = (g0 & 63) * 8 + (g0 >> 6);
      ushort_t h8[8], l8[8];
      #pragma unroll
      for (int j = 0; j < 8; ++j)
        split_bf16(Wo[(size_t)e * kDM + fbase + j * 8], h8[j], l8[j]);
      int4 hp, lp;
      hp.x = (int)((unsigned)h8[0] | ((unsigned)h8[1] << 16));
      hp.y = (int)((unsigned)h8[2] | ((unsigned)h8[3] << 16));
      hp.z = (int)((unsigned)h8[4] | ((unsigned)h8[5] << 16));
      hp.w = (int)((unsigned)h8[6] | ((unsigned)h8[7] << 16));
      lp.x = (int)((unsigned)l8[0] | ((unsigned)l8[1] << 16));
      lp.y = (int)((unsigned)l8[2] | ((unsigned)l8[3] << 16));
      lp.z = (int)((unsigned)l8[4] | ((unsigned)l8[5] << 16));
      lp.w = (int)((unsigned)l8[6] | ((unsigned)l8[7] << 16));
      *(int4*)&wo_h[(size_t)e * kDM + g0] = hp;
      *(int4*)&wo_l[(size_t)e * kDM + g0] = lp;
    }
    return;
  }

  __shared__ __align__(16) ushort_t Xh[64][72];
  __shared__ __align__(16) ushort_t Xl[64][72];
  const float* x    = (which == 1) ? xv : (which == 3 ? xq : xk);
  const float* W    = (which == 1) ? Wv : (which == 3 ? Wq : Wk);
  const float* bias = (which == 1) ? bv : (which == 3 ? bq : bk);
  const int h = blockIdx.y;
  const int t0g = blockIdx.x * 64;
  const int b = t0g >> 11, s0 = t0g & (kS - 1);
  const int tid  = threadIdx.x;
  const int w    = tid >> 6;
  const int lane = tid & 63;
  const int ln   = lane & 15;
  const int quad = lane >> 4;
  const size_t hb = ((size_t)b * kH + h) * (size_t)(kS * kD);

  #pragma unroll
  for (int cc = 0; cc < 4; ++cc) {
    const int id = tid + cc * 256;
    const int r = id >> 4, c = id & 15;
    const float4 v = *(const float4*)&x[((size_t)t0g + r) * kDM + h * kD + c * 4];
    ushort_t hh[4], ll[4];
    split_bf16(v.x, hh[0], ll[0]);
    split_bf16(v.y, hh[1], ll[1]);
    split_bf16(v.z, hh[2], ll[2]);
    split_bf16(v.w, hh[3], ll[3]);
    int2 hp, lp;
    hp.x = (int)((unsigned)hh[0] | ((unsigned)hh[1] << 16));
    hp.y = (int)((unsigned)hh[2] | ((unsigned)hh[3] << 16));
    lp.x = (int)((unsigned)ll[0] | ((unsigned)ll[1] << 16));
    lp.y = (int)((unsigned)ll[2] | ((unsigned)ll[3] << 16));
    *(int2*)&Xh[r][c * 4] = hp;
    *(int2*)&Xl[r][c * 4] = lp;
  }
  __syncthreads();

  f32x4 C[4];
  #pragma unroll
  for (int eb = 0; eb < 4; ++eb) C[eb] = (f32x4){0.f, 0.f, 0.f, 0.f};
  #pragma unroll
  for (int kc = 0; kc < 2; ++kc) {
    const s16x8 ah = *(const s16x8*)&Xh[w * 16 + ln][kc * 32 + quad * 8];
    const s16x8 al = *(const s16x8*)&Xl[w * 16 + ln][kc * 32 + quad * 8];
    #pragma unroll
    for (int eb = 0; eb < 4; ++eb) {
      const float* wp = &W[(size_t)(eb * 16 + ln) * kD + kc * 32 + quad * 8];
      const float4 w0 = *(const float4*)wp;
      const float4 w1 = *(const float4*)(wp + 4);
      const float ws[8] = {w0.x, w0.y, w0.z, w0.w, w1.x, w1.y, w1.z, w1.w};
      s16x8 bh, bl;
      #pragma unroll
      for (int j = 0; j < 8; ++j) {
        ushort_t hi, lo;
        split_bf16(ws[j], hi, lo);
        bh[j] = (short)hi; bl[j] = (short)lo;
      }
      C[eb] = __builtin_amdgcn_mfma_f32_16x16x32_bf16(ah, bh, C[eb], 0, 0, 0);
      C[eb] = __builtin_amdgcn_mfma_f32_16x16x32_bf16(ah, bl, C[eb], 0, 0, 0);
      C[eb] = __builtin_amdgcn_mfma_f32_16x16x32_bf16(al, bh, C[eb], 0, 0, 0);
    }
  }
  __syncthreads();

  if (which != 1) {
    ushort_t* dst = (which == 3) ? q_hi : k_hi;
    const float qsc = (which == 3) ? 0.25f : 1.0f;   // fold softmax scale into q
    #pragma unroll
    for (int eb = 0; eb < 4; ++eb) {
      const float be = bias[eb * 16 + ln];
      #pragma unroll
      for (int r = 0; r < 4; ++r)
        Xh[w * 16 + quad * 4 + r][eb * 16 + ln] = rne_bf16((C[eb][r] + be) * qsc);
    }
    __syncthreads();
    #pragma unroll
    for (int cc = 0; cc < 2; ++cc) {
      const int id = tid + cc * 256;
      const int r = id >> 3, c = id & 7;
      *(int4*)&dst[hb + (size_t)(s0 + r) * kD + c * 8] = *(int4*)&Xh[r][c * 8];
    }
  } else {
    #pragma unroll
    for (int eb = 0; eb < 4; ++eb) {
      const float be = bias[eb * 16 + ln];
      #pragma unroll
      for (int r = 0; r < 4; ++r)
        Xh[eb * 16 + ln][w * 16 + quad * 4 + r] = rne_bf16(C[eb][r] + be);
    }
    __syncthreads();
    #pragma unroll
    for (int cc = 0; cc < 2; ++cc) {
      const int id = tid + cc * 256;
      const int r = id >> 3, c = id & 7;
      *(int4*)&vt_hi[hb + (size_t)r * kS + s0 + c * 8] = *(int4*)&Xh[r][c * 8];
    }
  }
}

// ---------------------------------------------------------------------------
// Kernel 2: MFMA flash attention. Block 256 (4 waves), q-tile 128, wave owns
// 32 q-rows. Split-K x4: grid (S/128, H, B*4) = 1024 blocks, 3/CU (LDS).
// KVBLK=128 (R6's verified compute geometry, 8 barriers/block) with the
// register budget FIXED: only K is double-buffered (8 x int4 = 32 regs,
// same as R5); V + mask go through short-lived transients re-loaded per
// tile. Demand ~100 arch + 48 acc = 148 < 168 cap at (256,3) — R6's 16 x
// int4 full double-buffer (~164+) is what spilled. V-cur loads are issued
// BEFORE K-next prefetch so the V ds_write's vmcnt wait (issue-ordered)
// leaves the K-next loads in flight. exp scale pre-folded into q_hi.
// ---------------------------------------------------------------------------
__global__ __launch_bounds__(256, 3)
void attn_kernel(const ushort_t* __restrict__ q_hi,
                 const ushort_t* __restrict__ k_hi, const ushort_t* __restrict__ vt_hi,
                 const int* __restrict__ mask,
                 ushort_t* __restrict__ Opart, float* __restrict__ lws) {
  // smem: Kh[128][72] (18432B) | Vh[64][136] (17408B); QT[128][72] in epilogue.
  __shared__ __align__(16) ushort_t smem[128 * 72 + 64 * 136];
  __shared__ __align__(16) ushort_t Pbm[4 * 32 * 40];   // per-wave P (32q x 32k)
  __shared__ float Mz[128];
  ushort_t (*QT)[72]  = (ushort_t(*)[72])smem;
  ushort_t (*Kh)[72]  = (ushort_t(*)[72])smem;                  // [key][d]
  ushort_t (*Vh)[136] = (ushort_t(*)[136])(smem + 128 * 72);    // [d][key]
  ushort_t (*Pb)[32][40] = (ushort_t(*)[32][40])Pbm;

  const int tid  = threadIdx.x;
  const int w    = tid >> 6;          // wave 0..3
  const int lane = tid & 63;
  const int ln   = lane & 15;
  const int quad = lane >> 4;
  const int h    = blockIdx.y;
  const int b    = blockIdx.z >> 2;
  const int quarter = blockIdx.z & 3;
  const int q0   = blockIdx.x * 128;
  const size_t hb = ((size_t)b * kH + h) * (size_t)(kS * kD);

  // ---- Q fragments: direct from precomputed q_hi (bf16 [b,h,s,d]) ----
  s16x8 aqh[2][2];   // [group][db]
  #pragma unroll
  for (int g = 0; g < 2; ++g)
    #pragma unroll
    for (int db = 0; db < 2; ++db)
      aqh[g][db] = *(const s16x8*)
          &q_hi[hb + (size_t)(q0 + w * 32 + g * 16 + ln) * kD + db * 32 + quad * 8];

  f32x4 O[2][4];
  #pragma unroll
  for (int g = 0; g < 2; ++g)
    #pragma unroll
    for (int db = 0; db < 4; ++db) O[g][db] = (f32x4){0.f, 0.f, 0.f, 0.f};
  float rs[2][4] = {};

  // staging thread maps: K: 32 rows x 8 col-chunks; V: 16 d-rows x 16 key-chunks
  const int kr = tid >> 3, kc = (tid & 7) * 8;
  const int vr = tid >> 4, vc = (tid & 15) * 8;
  const ushort_t* gk0 = k_hi + hb + (size_t)kr * kD + kc;
  const ushort_t* gv0 = vt_hi + hb + (size_t)vr * kS + vc;
  const int kt0 = quarter * 4;        // tiles of 128 keys

// --- macros over NAMED register scalars (rule #20: no arrays/references) ---
#define PREFETCH_K(TT, K0, K1, K2, K3)                                        \
  {                                                                           \
    K0 = *(const int4*)&gk0[((size_t)(TT) * 128) * kD];                       \
    K1 = *(const int4*)&gk0[((size_t)(TT) * 128 + 32) * kD];                  \
    K2 = *(const int4*)&gk0[((size_t)(TT) * 128 + 64) * kD];                  \
    K3 = *(const int4*)&gk0[((size_t)(TT) * 128 + 96) * kD];                  \
  }

#define LOAD_VM(TT, V0, V1, V2, V3, MM)                                       \
  {                                                                           \
    V0 = *(const int4*)&gv0[(size_t)(TT) * 128];                              \
    V1 = *(const int4*)&gv0[16 * (size_t)kS + (size_t)(TT) * 128];            \
    V2 = *(const int4*)&gv0[32 * (size_t)kS + (size_t)(TT) * 128];            \
    V3 = *(const int4*)&gv0[48 * (size_t)kS + (size_t)(TT) * 128];            \
    if (tid < 128) MM = mask[(size_t)b * kS + (TT) * 128 + tid];              \
  }

#define STORE_K(K0, K1, K2, K3)                                               \
  {                                                                           \
    *(int4*)&Kh[kr][kc]      = K0;                                            \
    *(int4*)&Kh[kr + 32][kc] = K1;                                            \
    *(int4*)&Kh[kr + 64][kc] = K2;                                            \
    *(int4*)&Kh[kr + 96][kc] = K3;                                            \
  }

#define STORE_VM(V0, V1, V2, V3, MM)                                          \
  {                                                                           \
    *(int4*)&Vh[vr][vc]      = V0;                                            \
    *(int4*)&Vh[vr + 16][vc] = V1;                                            \
    *(int4*)&Vh[vr + 32][vc] = V2;                                            \
    *(int4*)&Vh[vr + 48][vc] = V3;                                            \
    if (tid < 128) Mz[tid] = (MM) ? 1.0f : 0.0f;                              \
  }

#define COMPUTE_TILE()                                                        \
  {                                                                           \
    _Pragma("unroll")                                                         \
    for (int h32 = 0; h32 < 4; ++h32) {                                       \
      f32x4 C[2][2];                                                          \
      _Pragma("unroll")                                                       \
      for (int g = 0; g < 2; ++g) {                                           \
        C[g][0] = (f32x4){0.f, 0.f, 0.f, 0.f};                                \
        C[g][1] = (f32x4){0.f, 0.f, 0.f, 0.f};                                \
      }                                                                       \
      __builtin_amdgcn_s_setprio(1);                                          \
      _Pragma("unroll")                                                       \
      for (int db = 0; db < 2; ++db) {                                        \
        const s16x8 bh0 = *(const s16x8*)&Kh[h32 * 32 + ln][db * 32 + quad * 8]; \
        const s16x8 bh1 = *(const s16x8*)&Kh[h32 * 32 + 16 + ln][db * 32 + quad * 8]; \
        _Pragma("unroll")                                                     \
        for (int g = 0; g < 2; ++g) {                                         \
          C[g][0] = __builtin_amdgcn_mfma_f32_16x16x32_bf16(aqh[g][db], bh0, C[g][0], 0, 0, 0); \
          C[g][1] = __builtin_amdgcn_mfma_f32_16x16x32_bf16(aqh[g][db], bh1, C[g][1], 0, 0, 0); \
        }                                                                     \
      }                                                                       \
      __builtin_amdgcn_s_setprio(0);                                          \
      _Pragma("unroll")                                                       \
      for (int g = 0; g < 2; ++g) {                                           \
        _Pragma("unroll")                                                     \
        for (int kb = 0; kb < 2; ++kb) {                                      \
          const float mz = Mz[h32 * 32 + kb * 16 + ln];                       \
          _Pragma("unroll")                                                   \
          for (int r = 0; r < 4; ++r) {                                       \
            const float p = mz * __expf(C[g][kb][r]);                         \
            union { float f; unsigned u; } pa; pa.f = p;                      \
            const unsigned tt = pa.u + 0x7fffu + ((pa.u >> 16) & 1u);         \
            Pb[w][g * 16 + quad * 4 + r][kb * 16 + ln] = (ushort_t)(tt >> 16); \
            union { unsigned u; float f; } pr; pr.u = tt & 0xffff0000u;       \
            rs[g][r] += pr.f;                                                 \
          }                                                                   \
        }                                                                     \
      }                                                                       \
      {                                                                       \
        const s16x8 ph0 = *(const s16x8*)&Pb[w][ln][quad * 8];                \
        const s16x8 ph1 = *(const s16x8*)&Pb[w][16 + ln][quad * 8];           \
        __builtin_amdgcn_s_setprio(1);                                        \
        _Pragma("unroll")                                                     \
        for (int db = 0; db < 4; ++db) {                                      \
          const s16x8 vh = *(const s16x8*)&Vh[db * 16 + ln][h32 * 32 + quad * 8]; \
          O[0][db] = __builtin_amdgcn_mfma_f32_16x16x32_bf16(ph0, vh, O[0][db], 0, 0, 0); \
          O[1][db] = __builtin_amdgcn_mfma_f32_16x16x32_bf16(ph1, vh, O[1][db], 0, 0, 0); \
        }                                                                     \
        __builtin_amdgcn_s_setprio(0);                                        \
      }                                                                       \
    }                                                                         \
  }

  int4 kA0, kA1, kA2, kA3, kB0, kB1, kB2, kB3;
  int4 v0, v1, v2, v3;
  int m0 = 0;
  PREFETCH_K(kt0, kA0, kA1, kA2, kA3);

  for (int i = 0; i < 2; ++i) {
    const int base = kt0 + i * 2;
    if (i) __syncthreads();                 // prev tile's LDS reads done
    LOAD_VM(base, v0, v1, v2, v3, m0);      // V-cur FIRST (older than K-next)
    PREFETCH_K(base + 1, kB0, kB1, kB2, kB3);
    STORE_K(kA0, kA1, kA2, kA3);
    STORE_VM(v0, v1, v2, v3, m0);
    __syncthreads();
    COMPUTE_TILE();
    __syncthreads();                        // tile A's LDS reads done
    LOAD_VM(base + 1, v0, v1, v2, v3, m0);
    if (i < 1) PREFETCH_K(base + 2, kA0, kA1, kA2, kA3);
    STORE_K(kB0, kB1, kB2, kB3);
    STORE_VM(v0, v1, v2, v3, m0);
    __syncthreads();
    COMPUTE_TILE();
  }

#undef PREFETCH_K
#undef LOAD_VM
#undef STORE_K
#undef STORE_VM
#undef COMPUTE_TILE

  // ---- l partials: 16-lane group reduce, plain store ----
  #pragma unroll
  for (int m = 1; m < 16; m <<= 1) {
    #pragma unroll
    for (int g = 0; g < 2; ++g)
      #pragma unroll
      for (int r = 0; r < 4; ++r) rs[g][r] += __shfl_xor(rs[g][r], m);
  }
  if (ln == 0) {
    #pragma unroll
    for (int g = 0; g < 2; ++g) {
      float* lp = lws + (size_t)quarter * kNL + ((size_t)b * kH + h) * kS +
                  q0 + w * 32 + g * 16 + quad * 4;
      #pragma unroll
      for (int r = 0; r < 4; ++r) lp[r] = rs[g][r];
    }
  }

  // ---- O partials: RNE bf16, LDS repack, coalesced stores ----
  __syncthreads();   // Kh/Vh dead
  #pragma unroll
  for (int g = 0; g < 2; ++g)
    #pragma unroll
    for (int db = 0; db < 4; ++db)
      #pragma unroll
      for (int r = 0; r < 4; ++r)
        QT[w * 32 + g * 16 + quad * 4 + r][db * 16 + ln] = rne_bf16(O[g][db][r]);
  __syncthreads();
  ushort_t* op = Opart + (size_t)quarter * kNE;
  #pragma unroll
  for (int cc = 0; cc < 4; ++cc) {
    const int id = tid + cc * 256;
    const int r = id >> 3, c = id & 7;
    *(int4*)&op[((size_t)b * kS + q0 + r) * kDM + h * kD + c * 8] = *(int4*)&QT[r][c * 8];
  }
}

// ---------------------------------------------------------------------------
// Kernel 3: MFMA output projection with fused split-K combine.
// t-tile 32, e-tile 128, k-step 32 -> Opart re-read factor 4.
// grid (B*S/32, DM/128), block 256 (4 waves: tsub = w&1, esub = w>>1).
// T14 register prefetch of next iteration's 8 global loads (kept from R0;
// cap here is 256 regs at (256,2) so no spill risk).
// ---------------------------------------------------------------------------
__global__ __launch_bounds__(256, 2)
void out_proj_kernel(const ushort_t* __restrict__ Opart, const float* __restrict__ lws,
                     const ushort_t* __restrict__ wh, const ushort_t* __restrict__ wl,
                     const float* __restrict__ bo, float* __restrict__ out) {
  __shared__ __align__(16) ushort_t Ah[32][40];
  __shared__ __align__(16) ushort_t Al[32][40];
  __shared__ __align__(16) ushort_t Bh[128][40];
  __shared__ __align__(16) ushort_t Bl[128][40];
  __shared__ float linv[kH][32];
  const int t0 = blockIdx.x * 32;
  const int e0 = blockIdx.y * 128;
  const int b  = t0 >> 11;
  const int s0 = t0 & (kS - 1);
  const int tid  = threadIdx.x;
  const int w    = tid >> 6;
  const int lane = tid & 63;
  const int ln   = lane & 15;
  const int quad = lane >> 4;
  const int tsub = w & 1;
  const int esub = w >> 1;

  {  // 8 heads x 32 rows: one l-sum per thread
    const int hh = tid >> 5, r = tid & 31;
    const size_t base = ((size_t)b * kH + hh) * kS + s0 + r;
    linv[hh][r] = 1.0f / (lws[base] + lws[kNL + base] +
                          lws[2 * kNL + base] + lws[3 * kNL + base]);
  }

  // per-thread staging coordinates (constant across the k-loop)
  const int ra  = tid >> 3, ca = (tid & 7) * 4;                   // A row/col4
  const int rb0 = tid >> 2, cb0 = (tid & 3) * 8;                  // B chunk 0
  const int rb1 = (tid + 256) >> 2, cb1 = ((tid + 256) & 3) * 8;  // B chunk 1
  const ushort_t* ap  = &Opart[(size_t)(t0 + ra) * kDM + ca];
  const ushort_t* bhp0 = &wh[(size_t)(e0 + rb0) * kDM + cb0];
  const ushort_t* blp0 = &wl[(size_t)(e0 + rb0) * kDM + cb0];
  const ushort_t* bhp1 = &wh[(size_t)(e0 + rb1) * kDM + cb1];
  const ushort_t* blp1 = &wl[(size_t)(e0 + rb1) * kDM + cb1];

  f32x4 C[4];
  #pragma unroll
  for (int eb = 0; eb < 4; ++eb) C[eb] = (f32x4){0.f, 0.f, 0.f, 0.f};

  // ---- prefetch k0 = 0 ----
  int2 pa0 = *(const int2*)(ap);
  int2 pa1 = *(const int2*)(ap + kNE);
  int2 pa2 = *(const int2*)(ap + 2 * kNE);
  int2 pa3 = *(const int2*)(ap + 3 * kNE);
  int4 pb0h = *(const int4*)(bhp0);
  int4 pb0l = *(const int4*)(blp0);
  int4 pb1h = *(const int4*)(bhp1);
  int4 pb1l = *(const int4*)(blp1);

  for (int k0 = 0; k0 < kDM; k0 += 32) {
    __syncthreads();
    // ---- consume prefetched A: sum 4 bf16 partials -> /l -> split ----
    {
      const int hh = k0 >> 6;
      float a0 = bf_to_f((unsigned)pa0.x & 0xffffu);
      float a1 = bf_to_f((unsigned)pa0.x >> 16);
      float a2 = bf_to_f((unsigned)pa0.y & 0xffffu);
      float a3 = bf_to_f((unsigned)pa0.y >> 16);
      a0 += bf_to_f((unsigned)pa1.x & 0xffffu);
      a1 += bf_to_f((unsigned)pa1.x >> 16);
      a2 += bf_to_f((unsigned)pa1.y & 0xffffu);
      a3 += bf_to_f((unsigned)pa1.y >> 16);
      a0 += bf_to_f((unsigned)pa2.x & 0xffffu);
      a1 += bf_to_f((unsigned)pa2.x >> 16);
      a2 += bf_to_f((unsigned)pa2.y & 0xffffu);
      a3 += bf_to_f((unsigned)pa2.y >> 16);
      a0 += bf_to_f((unsigned)pa3.x & 0xffffu);
      a1 += bf_to_f((unsigned)pa3.x >> 16);
      a2 += bf_to_f((unsigned)pa3.y & 0xffffu);
      a3 += bf_to_f((unsigned)pa3.y >> 16);
      const float li = linv[hh][ra];
      a0 *= li; a1 *= li; a2 *= li; a3 *= li;
      ushort_t h4[4], l4[4];
      split_bf16(a0, h4[0], l4[0]);
      split_bf16(a1, h4[1], l4[1]);
      split_bf16(a2, h4[2], l4[2]);
      split_bf16(a3, h4[3], l4[3]);
      int2 hp, lp;
      hp.x = (int)((unsigned)h4[0] | ((unsigned)h4[1] << 16));
      hp.y = (int)((unsigned)h4[2] | ((unsigned)h4[3] << 16));
      lp.x = (int)((unsigned)l4[0] | ((unsigned)l4[1] << 16));
      lp.y = (int)((unsigned)l4[2] | ((unsigned)l4[3] << 16));
      *(int2*)&Ah[ra][ca] = hp;
      *(int2*)&Al[ra][ca] = lp;
    }
    // ---- consume prefetched B ----
    *(int4*)&Bh[rb0][cb0] = pb0h;
    *(int4*)&Bl[rb0][cb0] = pb0l;
    *(int4*)&Bh[rb1][cb1] = pb1h;
    *(int4*)&Bl[rb1][cb1] = pb1l;
    // ---- issue next iteration's loads (latency hides under MFMA) ----
    if (k0 + 32 < kDM) {
      const int kn = k0 + 32;
      pa0 = *(const int2*)(ap + kn);
      pa1 = *(const int2*)(ap + kNE + kn);
      pa2 = *(const int2*)(ap + 2 * kNE + kn);
      pa3 = *(const int2*)(ap + 3 * kNE + kn);
      pb0h = *(const int4*)(bhp0 + kn);
      pb0l = *(const int4*)(blp0 + kn);
      pb1h = *(const int4*)(bhp1 + kn);
      pb1l = *(const int4*)(blp1 + kn);
    }
    __syncthreads();
    const s16x8 ah = *(const s16x8*)&Ah[tsub * 16 + ln][quad * 8];
    const s16x8 al = *(const s16x8*)&Al[tsub * 16 + ln][quad * 8];
    #pragma unroll
    for (int eb = 0; eb < 4; ++eb) {
      const s16x8 bh = *(const s16x8*)&Bh[esub * 64 + eb * 16 + ln][quad * 8];
      const s16x8 bl = *(const s16x8*)&Bl[esub * 64 + eb * 16 + ln][quad * 8];
      C[eb] = __builtin_amdgcn_mfma_f32_16x16x32_bf16(ah, bh, C[eb], 0, 0, 0);
      C[eb] = __builtin_amdgcn_mfma_f32_16x16x32_bf16(ah, bl, C[eb], 0, 0, 0);
      C[eb] = __builtin_amdgcn_mfma_f32_16x16x32_bf16(al, bh, C[eb], 0, 0, 0);
    }
  }

  #pragma unroll
  for (int eb = 0; eb < 4; ++eb) {
    const int e = e0 + esub * 64 + eb * 16 + ln;
    const float be = bo[e];
    #pragma unroll
    for (int r = 0; r < 4; ++r) {
      const int t = t0 + tsub * 16 + quad * 4 + r;
      out[(size_t)t * kDM + e] = C[eb][r] + be;
    }
  }
}

// ---------------------------------------------------------------------------
extern "C" void kernel_launch(void* const* d_in, const int* in_sizes, int n_in,
                              void* d_out, int out_size, void* d_ws, size_t ws_size,
                              hipStream_t stream) {
  const float* query = (const float*)d_in[0];
  const float* key   = (const float*)d_in[1];
  const float* value = (const float*)d_in[2];
  const float* Wq = (const float*)d_in[3];
  const float* bq = (const float*)d_in[4];
  const float* Wk = (const float*)d_in[5];
  const float* bk = (const float*)d_in[6];
  const float* Wv = (const float*)d_in[7];
  const float* bv = (const float*)d_in[8];
  const float* Wo = (const float*)d_in[9];
  const float* bo = (const float*)d_in[10];
  const int* mask = (const int*)d_in[11];
  float* out = (float*)d_out;

  ushort_t* k_hi  = (ushort_t*)d_ws;            // 4MB
  ushort_t* vt_hi = k_hi + kNE;                 // 4MB
  ushort_t* wo_h  = vt_hi + kNE;                // 512KB
  ushort_t* wo_l  = wo_h + (size_t)kDM * kDM;   // 512KB
  ushort_t* Opart = wo_l + (size_t)kDM * kDM;   // 16MB (4 quarters, bf16)
  float*    lws   = (float*)(Opart + 4 * kNE);  // 512KB (4 quarters)
  ushort_t* q_hi  = (ushort_t*)(lws + 4 * kNL); // 4MB   (total ~29.5 MB)

  proj_kernel<<<dim3(kB * kS / 64, kH, 4), 256, 0, stream>>>(
      key, value, query, Wk, bk, Wv, bv, Wq, bq, Wo, wo_h, wo_l, k_hi, vt_hi, q_hi);
  attn_kernel<<<dim3(kS / 128, kH, kB * 4), 256, 0, stream>>>(
      q_hi, k_hi, vt_hi, mask, Opart, lws);
  out_proj_kernel<<<dim3(kB * kS / 32, kDM / 128), 256, 0, stream>>>(
      Opart, lws, wo_h, wo_l, bo, out);
}

// Round 9
// 160.618 us; speedup vs baseline: 1.2972x; 1.1110x over previous
//
#include <hip/hip_runtime.h>
#include <math.h>

typedef float f32x4 __attribute__((ext_vector_type(4)));
typedef short s16x8 __attribute__((ext_vector_type(8)));
typedef unsigned short ushort_t;

namespace {
constexpr int kH  = 8;
constexpr int kD  = 64;
constexpr int kDM = 512;
constexpr int kB  = 2;
constexpr int kS  = 2048;
constexpr size_t kNE = (size_t)kB * kS * kDM;      // 2,097,152
constexpr size_t kNL = (size_t)kB * kH * kS;       // 32,768
}  // namespace

// Truncation split: x = hi + lo + eps, |eps| <= 2^-16 |x|
__device__ __forceinline__ void split_bf16(float x, ushort_t& hi, ushort_t& lo) {
  union { float f; unsigned u; } a; a.f = x;
  hi = (ushort_t)(a.u >> 16);
  union { unsigned u; float f; } hh; hh.u = a.u & 0xffff0000u;
  union { float f; unsigned u; } r; r.f = x - hh.f;
  lo = (ushort_t)(r.u >> 16);
}
// Round-to-nearest-even bf16
__device__ __forceinline__ ushort_t rne_bf16(float x) {
  union { float f; unsigned u; } a; a.f = x;
  const unsigned t = a.u + 0x7fffu + ((a.u >> 16) & 1u);
  return (ushort_t)(t >> 16);
}
__device__ __forceinline__ float bf_to_f(unsigned u16) {
  union { unsigned u; float f; } a; a.u = u16 << 16; return a.f;
}

// ---------------------------------------------------------------------------
// Kernel 1: Q/K/V projections via MFMA; W split in-register from fp32.
// grid (B*S/64, H, 4): z=0 -> k_hi [b,h,s,d]; z=1 -> vt_hi [b,h,d,key];
// z=2 -> Wo permuted split (blocks 0..127; rest idle); z=3 -> q_hi [b,h,s,d].
// q_hi is PRE-SCALED by 0.25 (the softmax scale): power-of-2, so the bf16
// split is bitwise-equivalent and attn can use __expf(S) with no mul.
// ---------------------------------------------------------------------------
__global__ __launch_bounds__(256, 2)
void proj_kernel(const float* __restrict__ xk, const float* __restrict__ xv,
                 const float* __restrict__ xq,
                 const float* __restrict__ Wk, const float* __restrict__ bk,
                 const float* __restrict__ Wv, const float* __restrict__ bv,
                 const float* __restrict__ Wq, const float* __restrict__ bq,
                 const float* __restrict__ Wo,
                 ushort_t* __restrict__ wo_h, ushort_t* __restrict__ wo_l,
                 ushort_t* __restrict__ k_hi, ushort_t* __restrict__ vt_hi,
                 ushort_t* __restrict__ q_hi) {
  const int which = blockIdx.z;
  if (which == 2) {
    const int bid = blockIdx.y * 64 + blockIdx.x;
    if (bid < 128) {
      // Wo permuted split: woP[e][g] = Wo[e][(g&63)*8 + (g>>6)]
      const int gi = (bid * 256 + threadIdx.x) * 8;
      const int e  = gi >> 9;
      const int g0 = gi & 511;
      const int fbase = (g0 & 63) * 8 + (g0 >> 6);
      ushort_t h8[8], l8[8];
      #pragma unroll
      for (int j = 0; j < 8; ++j)
        split_bf16(Wo[(size_t)e * kDM + fbase + j * 8], h8[j], l8[j]);
      int4 hp, lp;
      hp.x = (int)((unsigned)h8[0] | ((unsigned)h8[1] << 16));
      hp.y = (int)((unsigned)h8[2] | ((unsigned)h8[3] << 16));
      hp.z = (int)((unsigned)h8[4] | ((unsigned)h8[5] << 16));
      hp.w = (int)((unsigned)h8[6] | ((unsigned)h8[7] << 16));
      lp.x = (int)((unsigned)l8[0] | ((unsigned)l8[1] << 16));
      lp.y = (int)((unsigned)l8[2] | ((unsigned)l8[3] << 16));
      lp.z = (int)((unsigned)l8[4] | ((unsigned)l8[5] << 16));
      lp.w = (int)((unsigned)l8[6] | ((unsigned)l8[7] << 16));
      *(int4*)&wo_h[(size_t)e * kDM + g0] = hp;
      *(int4*)&wo_l[(size_t)e * kDM + g0] = lp;
    }
    return;
  }

  __shared__ __align__(16) ushort_t Xh[64][72];
  __shared__ __align__(16) ushort_t Xl[64][72];
  const float* x    = (which == 1) ? xv : (which == 3 ? xq : xk);
  const float* W    = (which == 1) ? Wv : (which == 3 ? Wq : Wk);
  const float* bias = (which == 1) ? bv : (which == 3 ? bq : bk);
  const int h = blockIdx.y;
  const int t0g = blockIdx.x * 64;
  const int b = t0g >> 11, s0 = t0g & (kS - 1);
  const int tid  = threadIdx.x;
  const int w    = tid >> 6;
  const int lane = tid & 63;
  const int ln   = lane & 15;
  const int quad = lane >> 4;
  const size_t hb = ((size_t)b * kH + h) * (size_t)(kS * kD);

  #pragma unroll
  for (int cc = 0; cc < 4; ++cc) {
    const int id = tid + cc * 256;
    const int r = id >> 4, c = id & 15;
    const float4 v = *(const float4*)&x[((size_t)t0g + r) * kDM + h * kD + c * 4];
    ushort_t hh[4], ll[4];
    split_bf16(v.x, hh[0], ll[0]);
    split_bf16(v.y, hh[1], ll[1]);
    split_bf16(v.z, hh[2], ll[2]);
    split_bf16(v.w, hh[3], ll[3]);
    int2 hp, lp;
    hp.x = (int)((unsigned)hh[0] | ((unsigned)hh[1] << 16));
    hp.y = (int)((unsigned)hh[2] | ((unsigned)hh[3] << 16));
    lp.x = (int)((unsigned)ll[0] | ((unsigned)ll[1] << 16));
    lp.y = (int)((unsigned)ll[2] | ((unsigned)ll[3] << 16));
    *(int2*)&Xh[r][c * 4] = hp;
    *(int2*)&Xl[r][c * 4] = lp;
  }
  __syncthreads();

  f32x4 C[4];
  #pragma unroll
  for (int eb = 0; eb < 4; ++eb) C[eb] = (f32x4){0.f, 0.f, 0.f, 0.f};
  #pragma unroll
  for (int kc = 0; kc < 2; ++kc) {
    const s16x8 ah = *(const s16x8*)&Xh[w * 16 + ln][kc * 32 + quad * 8];
    const s16x8 al = *(const s16x8*)&Xl[w * 16 + ln][kc * 32 + quad * 8];
    #pragma unroll
    for (int eb = 0; eb < 4; ++eb) {
      const float* wp = &W[(size_t)(eb * 16 + ln) * kD + kc * 32 + quad * 8];
      const float4 w0 = *(const float4*)wp;
      const float4 w1 = *(const float4*)(wp + 4);
      const float ws[8] = {w0.x, w0.y, w0.z, w0.w, w1.x, w1.y, w1.z, w1.w};
      s16x8 bh, bl;
      #pragma unroll
      for (int j = 0; j < 8; ++j) {
        ushort_t hi, lo;
        split_bf16(ws[j], hi, lo);
        bh[j] = (short)hi; bl[j] = (short)lo;
      }
      C[eb] = __builtin_amdgcn_mfma_f32_16x16x32_bf16(ah, bh, C[eb], 0, 0, 0);
      C[eb] = __builtin_amdgcn_mfma_f32_16x16x32_bf16(ah, bl, C[eb], 0, 0, 0);
      C[eb] = __builtin_amdgcn_mfma_f32_16x16x32_bf16(al, bh, C[eb], 0, 0, 0);
    }
  }
  __syncthreads();

  if (which != 1) {
    ushort_t* dst = (which == 3) ? q_hi : k_hi;
    const float qsc = (which == 3) ? 0.25f : 1.0f;   // fold softmax scale into q
    #pragma unroll
    for (int eb = 0; eb < 4; ++eb) {
      const float be = bias[eb * 16 + ln];
      #pragma unroll
      for (int r = 0; r < 4; ++r)
        Xh[w * 16 + quad * 4 + r][eb * 16 + ln] = rne_bf16((C[eb][r] + be) * qsc);
    }
    __syncthreads();
    #pragma unroll
    for (int cc = 0; cc < 2; ++cc) {
      const int id = tid + cc * 256;
      const int r = id >> 3, c = id & 7;
      *(int4*)&dst[hb + (size_t)(s0 + r) * kD + c * 8] = *(int4*)&Xh[r][c * 8];
    }
  } else {
    #pragma unroll
    for (int eb = 0; eb < 4; ++eb) {
      const float be = bias[eb * 16 + ln];
      #pragma unroll
      for (int r = 0; r < 4; ++r)
        Xh[eb * 16 + ln][w * 16 + quad * 4 + r] = rne_bf16(C[eb][r] + be);
    }
    __syncthreads();
    #pragma unroll
    for (int cc = 0; cc < 2; ++cc) {
      const int id = tid + cc * 256;
      const int r = id >> 3, c = id & 7;
      *(int4*)&vt_hi[hb + (size_t)r * kS + s0 + c * 8] = *(int4*)&Xh[r][c * 8];
    }
  }
}

// ---------------------------------------------------------------------------
// Kernel 2: MFMA flash attention — EXACT R5 structure (the only measured
// no-spill prefetch config: attn 46.0 us, VGPR 84, WRITE 25 MB). KVBLK=64,
// named-scalar K+V double-buffer, 4-iter x 2-tile runtime loop, (256,3).
// KVBLK=128 attempts (R6 full dbuf, R7 K-only) both spilled ~70-190 MB.
// Only delta vs R5: q_hi is pre-scaled 0.25 -> __expf(S) direct (-128 muls).
// ---------------------------------------------------------------------------
__global__ __launch_bounds__(256, 3)
void attn_kernel(const ushort_t* __restrict__ q_hi,
                 const ushort_t* __restrict__ k_hi, const ushort_t* __restrict__ vt_hi,
                 const int* __restrict__ mask,
                 ushort_t* __restrict__ Opart, float* __restrict__ lws) {
  // smem region (18432 B) is Kh|Vh in loop, QT in epilogue.
  __shared__ __align__(16) ushort_t smem[128 * 72];
  __shared__ __align__(16) ushort_t Pbm[4 * 32 * 40];   // per-wave P (32q x 32k)
  __shared__ float Mz[64];
  ushort_t (*QT)[72] = (ushort_t(*)[72])smem;
  ushort_t (*Kh)[72] = (ushort_t(*)[72])smem;              // [key][d]
  ushort_t (*Vh)[72] = (ushort_t(*)[72])(smem + 64 * 72);  // [d][key]
  ushort_t (*Pb)[32][40] = (ushort_t(*)[32][40])Pbm;

  const int tid  = threadIdx.x;
  const int w    = tid >> 6;          // wave 0..3
  const int lane = tid & 63;
  const int ln   = lane & 15;
  const int quad = lane >> 4;
  const int h    = blockIdx.y;
  const int b    = blockIdx.z >> 2;
  const int quarter = blockIdx.z & 3;
  const int q0   = blockIdx.x * 128;
  const size_t hb = ((size_t)b * kH + h) * (size_t)(kS * kD);

  // ---- Q fragments: direct from precomputed q_hi (bf16 [b,h,s,d]) ----
  s16x8 aqh[2][2];   // [group][db]
  #pragma unroll
  for (int g = 0; g < 2; ++g)
    #pragma unroll
    for (int db = 0; db < 2; ++db)
      aqh[g][db] = *(const s16x8*)
          &q_hi[hb + (size_t)(q0 + w * 32 + g * 16 + ln) * kD + db * 32 + quad * 8];

  f32x4 O[2][4];
  #pragma unroll
  for (int g = 0; g < 2; ++g)
    #pragma unroll
    for (int db = 0; db < 4; ++db) O[g][db] = (f32x4){0.f, 0.f, 0.f, 0.f};
  float rs[2][4] = {};

  // per-thread staging addresses (chunk adds 32 rows)
  const int sr = tid >> 3, sc = (tid & 7) * 8;
  const ushort_t* gk0 = k_hi + hb + (size_t)sr * kD + sc;
  const ushort_t* gv0 = vt_hi + hb + (size_t)sr * kS + sc;
  const int kt0 = quarter * 8;

// --- macros over NAMED register scalars (rule #20: no arrays/references) ---
#define PREFETCH_KV(TT, K0, K1, V0, V1, MM)                                   \
  {                                                                           \
    K0 = *(const int4*)&gk0[((size_t)(TT) * 64) * kD];                        \
    K1 = *(const int4*)&gk0[((size_t)(TT) * 64 + 32) * kD];                   \
    V0 = *(const int4*)&gv0[(size_t)(TT) * 64];                               \
    V1 = *(const int4*)&gv0[32 * (size_t)kS + (size_t)(TT) * 64];             \
    if (tid < 64) MM = mask[(size_t)b * kS + (TT) * 64 + tid];                \
  }

#define STORE_KV(K0, K1, V0, V1, MM)                                          \
  {                                                                           \
    *(int4*)&Kh[sr][sc] = K0;                                                 \
    *(int4*)&Kh[sr + 32][sc] = K1;                                            \
    *(int4*)&Vh[sr][sc] = V0;                                                 \
    *(int4*)&Vh[sr + 32][sc] = V1;                                            \
    if (tid < 64) Mz[tid] = (MM) ? 1.0f : 0.0f;                               \
  }

#define COMPUTE_TILE()                                                        \
  {                                                                           \
    _Pragma("unroll")                                                         \
    for (int h32 = 0; h32 < 2; ++h32) {                                       \
      f32x4 C[2][2];                                                          \
      _Pragma("unroll")                                                       \
      for (int g = 0; g < 2; ++g) {                                           \
        C[g][0] = (f32x4){0.f, 0.f, 0.f, 0.f};                                \
        C[g][1] = (f32x4){0.f, 0.f, 0.f, 0.f};                                \
      }                                                                       \
      __builtin_amdgcn_s_setprio(1);                                          \
      _Pragma("unroll")                                                       \
      for (int db = 0; db < 2; ++db) {                                        \
        const s16x8 bh0 = *(const s16x8*)&Kh[h32 * 32 + ln][db * 32 + quad * 8]; \
        const s16x8 bh1 = *(const s16x8*)&Kh[h32 * 32 + 16 + ln][db * 32 + quad * 8]; \
        _Pragma("unroll")                                                     \
        for (int g = 0; g < 2; ++g) {                                         \
          C[g][0] = __builtin_amdgcn_mfma_f32_16x16x32_bf16(aqh[g][db], bh0, C[g][0], 0, 0, 0); \
          C[g][1] = __builtin_amdgcn_mfma_f32_16x16x32_bf16(aqh[g][db], bh1, C[g][1], 0, 0, 0); \
        }                                                                     \
      }                                                                       \
      __builtin_amdgcn_s_setprio(0);                                          \
      _Pragma("unroll")                                                       \
      for (int g = 0; g < 2; ++g) {                                           \
        _Pragma("unroll")                                                     \
        for (int kb = 0; kb < 2; ++kb) {                                      \
          const float mz = Mz[h32 * 32 + kb * 16 + ln];                       \
          _Pragma("unroll")                                                   \
          for (int r = 0; r < 4; ++r) {                                       \
            const float p = mz * __expf(C[g][kb][r]);                         \
            union { float f; unsigned u; } pa; pa.f = p;                      \
            const unsigned tt = pa.u + 0x7fffu + ((pa.u >> 16) & 1u);         \
            Pb[w][g * 16 + quad * 4 + r][kb * 16 + ln] = (ushort_t)(tt >> 16); \
            union { unsigned u; float f; } pr; pr.u = tt & 0xffff0000u;       \
            rs[g][r] += pr.f;                                                 \
          }                                                                   \
        }                                                                     \
      }                                                                       \
      {                                                                       \
        const s16x8 ph0 = *(const s16x8*)&Pb[w][ln][quad * 8];                \
        const s16x8 ph1 = *(const s16x8*)&Pb[w][16 + ln][quad * 8];           \
        __builtin_amdgcn_s_setprio(1);                                        \
        _Pragma("unroll")                                                     \
        for (int db = 0; db < 4; ++db) {                                      \
          const s16x8 vh = *(const s16x8*)&Vh[db * 16 + ln][h32 * 32 + quad * 8]; \
          O[0][db] = __builtin_amdgcn_mfma_f32_16x16x32_bf16(ph0, vh, O[0][db], 0, 0, 0); \
          O[1][db] = __builtin_amdgcn_mfma_f32_16x16x32_bf16(ph1, vh, O[1][db], 0, 0, 0); \
        }                                                                     \
        __builtin_amdgcn_s_setprio(0);                                        \
      }                                                                       \
    }                                                                         \
  }

  int4 kA0, kA1, vA0, vA1, kB0, kB1, vB0, vB1;
  int mA = 0, mB = 0;
  PREFETCH_KV(kt0, kA0, kA1, vA0, vA1, mA);

  for (int i = 0; i < 4; ++i) {
    const int base = kt0 + i * 2;
    if (i) __syncthreads();                 // prev tile's LDS reads done
    PREFETCH_KV(base + 1, kB0, kB1, vB0, vB1, mB);   // in flight over tile A
    STORE_KV(kA0, kA1, vA0, vA1, mA);
    __syncthreads();
    COMPUTE_TILE();
    __syncthreads();                        // tile A's LDS reads done
    if (i < 3) PREFETCH_KV(base + 2, kA0, kA1, vA0, vA1, mA);  // over tile B
    STORE_KV(kB0, kB1, vB0, vB1, mB);
    __syncthreads();
    COMPUTE_TILE();
  }

#undef PREFETCH_KV
#undef STORE_KV
#undef COMPUTE_TILE

  // ---- l partials: 16-lane group reduce, plain store ----
  #pragma unroll
  for (int m = 1; m < 16; m <<= 1) {
    #pragma unroll
    for (int g = 0; g < 2; ++g)
      #pragma unroll
      for (int r = 0; r < 4; ++r) rs[g][r] += __shfl_xor(rs[g][r], m);
  }
  if (ln == 0) {
    #pragma unroll
    for (int g = 0; g < 2; ++g) {
      float* lp = lws + (size_t)quarter * kNL + ((size_t)b * kH + h) * kS +
                  q0 + w * 32 + g * 16 + quad * 4;
      #pragma unroll
      for (int r = 0; r < 4; ++r) lp[r] = rs[g][r];
    }
  }

  // ---- O partials: RNE bf16, LDS repack, coalesced stores ----
  __syncthreads();   // Kh/Vh dead
  #pragma unroll
  for (int g = 0; g < 2; ++g)
    #pragma unroll
    for (int db = 0; db < 4; ++db)
      #pragma unroll
      for (int r = 0; r < 4; ++r)
        QT[w * 32 + g * 16 + quad * 4 + r][db * 16 + ln] = rne_bf16(O[g][db][r]);
  __syncthreads();
  ushort_t* op = Opart + (size_t)quarter * kNE;
  #pragma unroll
  for (int cc = 0; cc < 4; ++cc) {
    const int id = tid + cc * 256;
    const int r = id >> 3, c = id & 7;
    *(int4*)&op[((size_t)b * kS + q0 + r) * kDM + h * kD + c * 8] = *(int4*)&QT[r][c * 8];
  }
}

// ---------------------------------------------------------------------------
// Kernel 3: MFMA output projection with fused split-K combine.
// t-tile 32, e-tile 128, k-step 32 -> Opart re-read factor 4.
// grid (B*S/32, DM/128), block 256 (4 waves: tsub = w&1, esub = w>>1).
// T14 register prefetch of next iteration's 8 global loads (kept from R0;
// cap here is 256 regs at (256,2) so no spill risk).
// ---------------------------------------------------------------------------
__global__ __launch_bounds__(256, 2)
void out_proj_kernel(const ushort_t* __restrict__ Opart, const float* __restrict__ lws,
                     const ushort_t* __restrict__ wh, const ushort_t* __restrict__ wl,
                     const float* __restrict__ bo, float* __restrict__ out) {
  __shared__ __align__(16) ushort_t Ah[32][40];
  __shared__ __align__(16) ushort_t Al[32][40];
  __shared__ __align__(16) ushort_t Bh[128][40];
  __shared__ __align__(16) ushort_t Bl[128][40];
  __shared__ float linv[kH][32];
  const int t0 = blockIdx.x * 32;
  const int e0 = blockIdx.y * 128;
  const int b  = t0 >> 11;
  const int s0 = t0 & (kS - 1);
  const int tid  = threadIdx.x;
  const int w    = tid >> 6;
  const int lane = tid & 63;
  const int ln   = lane & 15;
  const int quad = lane >> 4;
  const int tsub = w & 1;
  const int esub = w >> 1;

  {  // 8 heads x 32 rows: one l-sum per thread
    const int hh = tid >> 5, r = tid & 31;
    const size_t base = ((size_t)b * kH + hh) * kS + s0 + r;
    linv[hh][r] = 1.0f / (lws[base] + lws[kNL + base] +
                          lws[2 * kNL + base] + lws[3 * kNL + base]);
  }

  // per-thread staging coordinates (constant across the k-loop)
  const int ra  = tid >> 3, ca = (tid & 7) * 4;                   // A row/col4
  const int rb0 = tid >> 2, cb0 = (tid & 3) * 8;                  // B chunk 0
  const int rb1 = (tid + 256) >> 2, cb1 = ((tid + 256) & 3) * 8;  // B chunk 1
  const ushort_t* ap  = &Opart[(size_t)(t0 + ra) * kDM + ca];
  const ushort_t* bhp0 = &wh[(size_t)(e0 + rb0) * kDM + cb0];
  const ushort_t* blp0 = &wl[(size_t)(e0 + rb0) * kDM + cb0];
  const ushort_t* bhp1 = &wh[(size_t)(e0 + rb1) * kDM + cb1];
  const ushort_t* blp1 = &wl[(size_t)(e0 + rb1) * kDM + cb1];

  f32x4 C[4];
  #pragma unroll
  for (int eb = 0; eb < 4; ++eb) C[eb] = (f32x4){0.f, 0.f, 0.f, 0.f};

  // ---- prefetch k0 = 0 ----
  int2 pa0 = *(const int2*)(ap);
  int2 pa1 = *(const int2*)(ap + kNE);
  int2 pa2 = *(const int2*)(ap + 2 * kNE);
  int2 pa3 = *(const int2*)(ap + 3 * kNE);
  int4 pb0h = *(const int4*)(bhp0);
  int4 pb0l = *(const int4*)(blp0);
  int4 pb1h = *(const int4*)(bhp1);
  int4 pb1l = *(const int4*)(blp1);

  for (int k0 = 0; k0 < kDM; k0 += 32) {
    __syncthreads();
    // ---- consume prefetched A: sum 4 bf16 partials -> /l -> split ----
    {
      const int hh = k0 >> 6;
      float a0 = bf_to_f((unsigned)pa0.x & 0xffffu);
      float a1 = bf_to_f((unsigned)pa0.x >> 16);
      float a2 = bf_to_f((unsigned)pa0.y & 0xffffu);
      float a3 = bf_to_f((unsigned)pa0.y >> 16);
      a0 += bf_to_f((unsigned)pa1.x & 0xffffu);
      a1 += bf_to_f((unsigned)pa1.x >> 16);
      a2 += bf_to_f((unsigned)pa1.y & 0xffffu);
      a3 += bf_to_f((unsigned)pa1.y >> 16);
      a0 += bf_to_f((unsigned)pa2.x & 0xffffu);
      a1 += bf_to_f((unsigned)pa2.x >> 16);
      a2 += bf_to_f((unsigned)pa2.y & 0xffffu);
      a3 += bf_to_f((unsigned)pa2.y >> 16);
      a0 += bf_to_f((unsigned)pa3.x & 0xffffu);
      a1 += bf_to_f((unsigned)pa3.x >> 16);
      a2 += bf_to_f((unsigned)pa3.y & 0xffffu);
      a3 += bf_to_f((unsigned)pa3.y >> 16);
      const float li = linv[hh][ra];
      a0 *= li; a1 *= li; a2 *= li; a3 *= li;
      ushort_t h4[4], l4[4];
      split_bf16(a0, h4[0], l4[0]);
      split_bf16(a1, h4[1], l4[1]);
      split_bf16(a2, h4[2], l4[2]);
      split_bf16(a3, h4[3], l4[3]);
      int2 hp, lp;
      hp.x = (int)((unsigned)h4[0] | ((unsigned)h4[1] << 16));
      hp.y = (int)((unsigned)h4[2] | ((unsigned)h4[3] << 16));
      lp.x = (int)((unsigned)l4[0] | ((unsigned)l4[1] << 16));
      lp.y = (int)((unsigned)l4[2] | ((unsigned)l4[3] << 16));
      *(int2*)&Ah[ra][ca] = hp;
      *(int2*)&Al[ra][ca] = lp;
    }
    // ---- consume prefetched B ----
    *(int4*)&Bh[rb0][cb0] = pb0h;
    *(int4*)&Bl[rb0][cb0] = pb0l;
    *(int4*)&Bh[rb1][cb1] = pb1h;
    *(int4*)&Bl[rb1][cb1] = pb1l;
    // ---- issue next iteration's loads (latency hides under MFMA) ----
    if (k0 + 32 < kDM) {
      const int kn = k0 + 32;
      pa0 = *(const int2*)(ap + kn);
      pa1 = *(const int2*)(ap + kNE + kn);
      pa2 = *(const int2*)(ap + 2 * kNE + kn);
      pa3 = *(const int2*)(ap + 3 * kNE + kn);
      pb0h = *(const int4*)(bhp0 + kn);
      pb0l = *(const int4*)(blp0 + kn);
      pb1h = *(const int4*)(bhp1 + kn);
      pb1l = *(const int4*)(blp1 + kn);
    }
    __syncthreads();
    const s16x8 ah = *(const s16x8*)&Ah[tsub * 16 + ln][quad * 8];
    const s16x8 al = *(const s16x8*)&Al[tsub * 16 + ln][quad * 8];
    #pragma unroll
    for (int eb = 0; eb < 4; ++eb) {
      const s16x8 bh = *(const s16x8*)&Bh[esub * 64 + eb * 16 + ln][quad * 8];
      const s16x8 bl = *(const s16x8*)&Bl[esub * 64 + eb * 16 + ln][quad * 8];
      C[eb] = __builtin_amdgcn_mfma_f32_16x16x32_bf16(ah, bh, C[eb], 0, 0, 0);
      C[eb] = __builtin_amdgcn_mfma_f32_16x16x32_bf16(ah, bl, C[eb], 0, 0, 0);
      C[eb] = __builtin_amdgcn_mfma_f32_16x16x32_bf16(al, bh, C[eb], 0, 0, 0);
    }
  }

  #pragma unroll
  for (int eb = 0; eb < 4; ++eb) {
    const int e = e0 + esub * 64 + eb * 16 + ln;
    const float be = bo[e];
    #pragma unroll
    for (int r = 0; r < 4; ++r) {
      const int t = t0 + tsub * 16 + quad * 4 + r;
      out[(size_t)t * kDM + e] = C[eb][r] + be;
    }
  }
}

// ---------------------------------------------------------------------------
extern "C" void kernel_launch(void* const* d_in, const int* in_sizes, int n_in,
                              void* d_out, int out_size, void* d_ws, size_t ws_size,
                              hipStream_t stream) {
  const float* query = (const float*)d_in[0];
  const float* key   = (const float*)d_in[1];
  const float* value = (const float*)d_in[2];
  const float* Wq = (const float*)d_in[3];
  const float* bq = (const float*)d_in[4];
  const float* Wk = (const float*)d_in[5];
  const float* bk = (const float*)d_in[6];
  const float* Wv = (const float*)d_in[7];
  const float* bv = (const float*)d_in[8];
  const float* Wo = (const float*)d_in[9];
  const float* bo = (const float*)d_in[10];
  const int* mask = (const int*)d_in[11];
  float* out = (float*)d_out;

  ushort_t* k_hi  = (ushort_t*)d_ws;            // 4MB
  ushort_t* vt_hi = k_hi + kNE;                 // 4MB
  ushort_t* wo_h  = vt_hi + kNE;                // 512KB
  ushort_t* wo_l  = wo_h + (size_t)kDM * kDM;   // 512KB
  ushort_t* Opart = wo_l + (size_t)kDM * kDM;   // 16MB (4 quarters, bf16)
  float*    lws   = (float*)(Opart + 4 * kNE);  // 512KB (4 quarters)
  ushort_t* q_hi  = (ushort_t*)(lws + 4 * kNL); // 4MB   (total ~29.5 MB)

  proj_kernel<<<dim3(kB * kS / 64, kH, 4), 256, 0, stream>>>(
      key, value, query, Wk, bk, Wv, bv, Wq, bq, Wo, wo_h, wo_l, k_hi, vt_hi, q_hi);
  attn_kernel<<<dim3(kS / 128, kH, kB * 4), 256, 0, stream>>>(
      q_hi, k_hi, vt_hi, mask, Opart, lws);
  out_proj_kernel<<<dim3(kB * kS / 32, kDM / 128), 256, 0, stream>>>(
      Opart, lws, wo_h, wo_l, bo, out);
}

// Round 10
// 158.889 us; speedup vs baseline: 1.3113x; 1.0109x over previous
//
#include <hip/hip_runtime.h>
#include <math.h>

typedef float f32x4 __attribute__((ext_vector_type(4)));
typedef short s16x8 __attribute__((ext_vector_type(8)));
typedef unsigned short ushort_t;

namespace {
constexpr int kH  = 8;
constexpr int kD  = 64;
constexpr int kDM = 512;
constexpr int kB  = 2;
constexpr int kS  = 2048;
constexpr size_t kNE = (size_t)kB * kS * kDM;      // 2,097,152
constexpr size_t kNL = (size_t)kB * kH * kS;       // 32,768
}  // namespace

// Truncation split: x = hi + lo + eps, |eps| <= 2^-16 |x|
__device__ __forceinline__ void split_bf16(float x, ushort_t& hi, ushort_t& lo) {
  union { float f; unsigned u; } a; a.f = x;
  hi = (ushort_t)(a.u >> 16);
  union { unsigned u; float f; } hh; hh.u = a.u & 0xffff0000u;
  union { float f; unsigned u; } r; r.f = x - hh.f;
  lo = (ushort_t)(r.u >> 16);
}
// Round-to-nearest-even bf16
__device__ __forceinline__ ushort_t rne_bf16(float x) {
  union { float f; unsigned u; } a; a.f = x;
  const unsigned t = a.u + 0x7fffu + ((a.u >> 16) & 1u);
  return (ushort_t)(t >> 16);
}
__device__ __forceinline__ float bf_to_f(unsigned u16) {
  union { unsigned u; float f; } a; a.u = u16 << 16; return a.f;
}

// ---------------------------------------------------------------------------
// Kernel 1: Q/K/V projections via MFMA; W split in-register from fp32.
// grid (B*S/64, H, 4): z=0 -> k_hi [b,h,s,d]; z=1 -> vt_hi [b,h,d,key];
// z=2 -> Wo permuted split (blocks 0..127; rest idle); z=3 -> q_hi [b,h,s,d].
// q_hi is PRE-SCALED by 0.25 (the softmax scale): power-of-2, so the bf16
// split is bitwise-equivalent and attn can use __expf(S) with no mul.
// ---------------------------------------------------------------------------
__global__ __launch_bounds__(256, 2)
void proj_kernel(const float* __restrict__ xk, const float* __restrict__ xv,
                 const float* __restrict__ xq,
                 const float* __restrict__ Wk, const float* __restrict__ bk,
                 const float* __restrict__ Wv, const float* __restrict__ bv,
                 const float* __restrict__ Wq, const float* __restrict__ bq,
                 const float* __restrict__ Wo,
                 ushort_t* __restrict__ wo_h, ushort_t* __restrict__ wo_l,
                 ushort_t* __restrict__ k_hi, ushort_t* __restrict__ vt_hi,
                 ushort_t* __restrict__ q_hi) {
  const int which = blockIdx.z;
  if (which == 2) {
    const int bid = blockIdx.y * 64 + blockIdx.x;
    if (bid < 128) {
      // Wo permuted split: woP[e][g] = Wo[e][(g&63)*8 + (g>>6)]
      const int gi = (bid * 256 + threadIdx.x) * 8;
      const int e  = gi >> 9;
      const int g0 = gi & 511;
      const int fbase = (g0 & 63) * 8 + (g0 >> 6);
      ushort_t h8[8], l8[8];
      #pragma unroll
      for (int j = 0; j < 8; ++j)
        split_bf16(Wo[(size_t)e * kDM + fbase + j * 8], h8[j], l8[j]);
      int4 hp, lp;
      hp.x = (int)((unsigned)h8[0] | ((unsigned)h8[1] << 16));
      hp.y = (int)((unsigned)h8[2] | ((unsigned)h8[3] << 16));
      hp.z = (int)((unsigned)h8[4] | ((unsigned)h8[5] << 16));
      hp.w = (int)((unsigned)h8[6] | ((unsigned)h8[7] << 16));
      lp.x = (int)((unsigned)l8[0] | ((unsigned)l8[1] << 16));
      lp.y = (int)((unsigned)l8[2] | ((unsigned)l8[3] << 16));
      lp.z = (int)((unsigned)l8[4] | ((unsigned)l8[5] << 16));
      lp.w = (int)((unsigned)l8[6] | ((unsigned)l8[7] << 16));
      *(int4*)&wo_h[(size_t)e * kDM + g0] = hp;
      *(int4*)&wo_l[(size_t)e * kDM + g0] = lp;
    }
    return;
  }

  __shared__ __align__(16) ushort_t Xh[64][72];
  __shared__ __align__(16) ushort_t Xl[64][72];
  const float* x    = (which == 1) ? xv : (which == 3 ? xq : xk);
  const float* W    = (which == 1) ? Wv : (which == 3 ? Wq : Wk);
  const float* bias = (which == 1) ? bv : (which == 3 ? bq : bk);
  const int h = blockIdx.y;
  const int t0g = blockIdx.x * 64;
  const int b = t0g >> 11, s0 = t0g & (kS - 1);
  const int tid  = threadIdx.x;
  const int w    = tid >> 6;
  const int lane = tid & 63;
  const int ln   = lane & 15;
  const int quad = lane >> 4;
  const size_t hb = ((size_t)b * kH + h) * (size_t)(kS * kD);

  #pragma unroll
  for (int cc = 0; cc < 4; ++cc) {
    const int id = tid + cc * 256;
    const int r = id >> 4, c = id & 15;
    const float4 v = *(const float4*)&x[((size_t)t0g + r) * kDM + h * kD + c * 4];
    ushort_t hh[4], ll[4];
    split_bf16(v.x, hh[0], ll[0]);
    split_bf16(v.y, hh[1], ll[1]);
    split_bf16(v.z, hh[2], ll[2]);
    split_bf16(v.w, hh[3], ll[3]);
    int2 hp, lp;
    hp.x = (int)((unsigned)hh[0] | ((unsigned)hh[1] << 16));
    hp.y = (int)((unsigned)hh[2] | ((unsigned)hh[3] << 16));
    lp.x = (int)((unsigned)ll[0] | ((unsigned)ll[1] << 16));
    lp.y = (int)((unsigned)ll[2] | ((unsigned)ll[3] << 16));
    *(int2*)&Xh[r][c * 4] = hp;
    *(int2*)&Xl[r][c * 4] = lp;
  }
  __syncthreads();

  f32x4 C[4];
  #pragma unroll
  for (int eb = 0; eb < 4; ++eb) C[eb] = (f32x4){0.f, 0.f, 0.f, 0.f};
  #pragma unroll
  for (int kc = 0; kc < 2; ++kc) {
    const s16x8 ah = *(const s16x8*)&Xh[w * 16 + ln][kc * 32 + quad * 8];
    const s16x8 al = *(const s16x8*)&Xl[w * 16 + ln][kc * 32 + quad * 8];
    #pragma unroll
    for (int eb = 0; eb < 4; ++eb) {
      const float* wp = &W[(size_t)(eb * 16 + ln) * kD + kc * 32 + quad * 8];
      const float4 w0 = *(const float4*)wp;
      const float4 w1 = *(const float4*)(wp + 4);
      const float ws[8] = {w0.x, w0.y, w0.z, w0.w, w1.x, w1.y, w1.z, w1.w};
      s16x8 bh, bl;
      #pragma unroll
      for (int j = 0; j < 8; ++j) {
        ushort_t hi, lo;
        split_bf16(ws[j], hi, lo);
        bh[j] = (short)hi; bl[j] = (short)lo;
      }
      C[eb] = __builtin_amdgcn_mfma_f32_16x16x32_bf16(ah, bh, C[eb], 0, 0, 0);
      C[eb] = __builtin_amdgcn_mfma_f32_16x16x32_bf16(ah, bl, C[eb], 0, 0, 0);
      C[eb] = __builtin_amdgcn_mfma_f32_16x16x32_bf16(al, bh, C[eb], 0, 0, 0);
    }
  }
  __syncthreads();

  if (which != 1) {
    ushort_t* dst = (which == 3) ? q_hi : k_hi;
    const float qsc = (which == 3) ? 0.25f : 1.0f;   // fold softmax scale into q
    #pragma unroll
    for (int eb = 0; eb < 4; ++eb) {
      const float be = bias[eb * 16 + ln];
      #pragma unroll
      for (int r = 0; r < 4; ++r)
        Xh[w * 16 + quad * 4 + r][eb * 16 + ln] = rne_bf16((C[eb][r] + be) * qsc);
    }
    __syncthreads();
    #pragma unroll
    for (int cc = 0; cc < 2; ++cc) {
      const int id = tid + cc * 256;
      const int r = id >> 3, c = id & 7;
      *(int4*)&dst[hb + (size_t)(s0 + r) * kD + c * 8] = *(int4*)&Xh[r][c * 8];
    }
  } else {
    #pragma unroll
    for (int eb = 0; eb < 4; ++eb) {
      const float be = bias[eb * 16 + ln];
      #pragma unroll
      for (int r = 0; r < 4; ++r)
        Xh[eb * 16 + ln][w * 16 + quad * 4 + r] = rne_bf16(C[eb][r] + be);
    }
    __syncthreads();
    #pragma unroll
    for (int cc = 0; cc < 2; ++cc) {
      const int id = tid + cc * 256;
      const int r = id >> 3, c = id & 7;
      *(int4*)&vt_hi[hb + (size_t)r * kS + s0 + c * 8] = *(int4*)&Xh[r][c * 8];
    }
  }
}

// ---------------------------------------------------------------------------
// Kernel 2: MFMA flash attention — EXACT R9 structure (stable plateau:
// 46-52 us band, VGPR 84, no spill). KVBLK=64, named-scalar K+V double
// buffer, (256,3), q_hi pre-scaled -> __expf(S) direct. DO NOT TOUCH:
// every KVBLK=128 variant spilled; this is the measured-good config.
// ---------------------------------------------------------------------------
__global__ __launch_bounds__(256, 3)
void attn_kernel(const ushort_t* __restrict__ q_hi,
                 const ushort_t* __restrict__ k_hi, const ushort_t* __restrict__ vt_hi,
                 const int* __restrict__ mask,
                 ushort_t* __restrict__ Opart, float* __restrict__ lws) {
  // smem region (18432 B) is Kh|Vh in loop, QT in epilogue.
  __shared__ __align__(16) ushort_t smem[128 * 72];
  __shared__ __align__(16) ushort_t Pbm[4 * 32 * 40];   // per-wave P (32q x 32k)
  __shared__ float Mz[64];
  ushort_t (*QT)[72] = (ushort_t(*)[72])smem;
  ushort_t (*Kh)[72] = (ushort_t(*)[72])smem;              // [key][d]
  ushort_t (*Vh)[72] = (ushort_t(*)[72])(smem + 64 * 72);  // [d][key]
  ushort_t (*Pb)[32][40] = (ushort_t(*)[32][40])Pbm;

  const int tid  = threadIdx.x;
  const int w    = tid >> 6;          // wave 0..3
  const int lane = tid & 63;
  const int ln   = lane & 15;
  const int quad = lane >> 4;
  const int h    = blockIdx.y;
  const int b    = blockIdx.z >> 2;
  const int quarter = blockIdx.z & 3;
  const int q0   = blockIdx.x * 128;
  const size_t hb = ((size_t)b * kH + h) * (size_t)(kS * kD);

  // ---- Q fragments: direct from precomputed q_hi (bf16 [b,h,s,d]) ----
  s16x8 aqh[2][2];   // [group][db]
  #pragma unroll
  for (int g = 0; g < 2; ++g)
    #pragma unroll
    for (int db = 0; db < 2; ++db)
      aqh[g][db] = *(const s16x8*)
          &q_hi[hb + (size_t)(q0 + w * 32 + g * 16 + ln) * kD + db * 32 + quad * 8];

  f32x4 O[2][4];
  #pragma unroll
  for (int g = 0; g < 2; ++g)
    #pragma unroll
    for (int db = 0; db < 4; ++db) O[g][db] = (f32x4){0.f, 0.f, 0.f, 0.f};
  float rs[2][4] = {};

  // per-thread staging addresses (chunk adds 32 rows)
  const int sr = tid >> 3, sc = (tid & 7) * 8;
  const ushort_t* gk0 = k_hi + hb + (size_t)sr * kD + sc;
  const ushort_t* gv0 = vt_hi + hb + (size_t)sr * kS + sc;
  const int kt0 = quarter * 8;

// --- macros over NAMED register scalars (rule #20: no arrays/references) ---
#define PREFETCH_KV(TT, K0, K1, V0, V1, MM)                                   \
  {                                                                           \
    K0 = *(const int4*)&gk0[((size_t)(TT) * 64) * kD];                        \
    K1 = *(const int4*)&gk0[((size_t)(TT) * 64 + 32) * kD];                   \
    V0 = *(const int4*)&gv0[(size_t)(TT) * 64];                               \
    V1 = *(const int4*)&gv0[32 * (size_t)kS + (size_t)(TT) * 64];             \
    if (tid < 64) MM = mask[(size_t)b * kS + (TT) * 64 + tid];                \
  }

#define STORE_KV(K0, K1, V0, V1, MM)                                          \
  {                                                                           \
    *(int4*)&Kh[sr][sc] = K0;                                                 \
    *(int4*)&Kh[sr + 32][sc] = K1;                                            \
    *(int4*)&Vh[sr][sc] = V0;                                                 \
    *(int4*)&Vh[sr + 32][sc] = V1;                                            \
    if (tid < 64) Mz[tid] = (MM) ? 1.0f : 0.0f;                               \
  }

#define COMPUTE_TILE()                                                        \
  {                                                                           \
    _Pragma("unroll")                                                         \
    for (int h32 = 0; h32 < 2; ++h32) {                                       \
      f32x4 C[2][2];                                                          \
      _Pragma("unroll")                                                       \
      for (int g = 0; g < 2; ++g) {                                           \
        C[g][0] = (f32x4){0.f, 0.f, 0.f, 0.f};                                \
        C[g][1] = (f32x4){0.f, 0.f, 0.f, 0.f};                                \
      }                                                                       \
      __builtin_amdgcn_s_setprio(1);                                          \
      _Pragma("unroll")                                                       \
      for (int db = 0; db < 2; ++db) {                                        \
        const s16x8 bh0 = *(const s16x8*)&Kh[h32 * 32 + ln][db * 32 + quad * 8]; \
        const s16x8 bh1 = *(const s16x8*)&Kh[h32 * 32 + 16 + ln][db * 32 + quad * 8]; \
        _Pragma("unroll")                                                     \
        for (int g = 0; g < 2; ++g) {                                         \
          C[g][0] = __builtin_amdgcn_mfma_f32_16x16x32_bf16(aqh[g][db], bh0, C[g][0], 0, 0, 0); \
          C[g][1] = __builtin_amdgcn_mfma_f32_16x16x32_bf16(aqh[g][db], bh1, C[g][1], 0, 0, 0); \
        }                                                                     \
      }                                                                       \
      __builtin_amdgcn_s_setprio(0);                                          \
      _Pragma("unroll")                                                       \
      for (int g = 0; g < 2; ++g) {                                           \
        _Pragma("unroll")                                                     \
        for (int kb = 0; kb < 2; ++kb) {                                      \
          const float mz = Mz[h32 * 32 + kb * 16 + ln];                       \
          _Pragma("unroll")                                                   \
          for (int r = 0; r < 4; ++r) {                                       \
            const float p = mz * __expf(C[g][kb][r]);                         \
            union { float f; unsigned u; } pa; pa.f = p;                      \
            const unsigned tt = pa.u + 0x7fffu + ((pa.u >> 16) & 1u);         \
            Pb[w][g * 16 + quad * 4 + r][kb * 16 + ln] = (ushort_t)(tt >> 16); \
            union { unsigned u; float f; } pr; pr.u = tt & 0xffff0000u;       \
            rs[g][r] += pr.f;                                                 \
          }                                                                   \
        }                                                                     \
      }                                                                       \
      {                                                                       \
        const s16x8 ph0 = *(const s16x8*)&Pb[w][ln][quad * 8];                \
        const s16x8 ph1 = *(const s16x8*)&Pb[w][16 + ln][quad * 8];           \
        __builtin_amdgcn_s_setprio(1);                                        \
        _Pragma("unroll")                                                     \
        for (int db = 0; db < 4; ++db) {                                      \
          const s16x8 vh = *(const s16x8*)&Vh[db * 16 + ln][h32 * 32 + quad * 8]; \
          O[0][db] = __builtin_amdgcn_mfma_f32_16x16x32_bf16(ph0, vh, O[0][db], 0, 0, 0); \
          O[1][db] = __builtin_amdgcn_mfma_f32_16x16x32_bf16(ph1, vh, O[1][db], 0, 0, 0); \
        }                                                                     \
        __builtin_amdgcn_s_setprio(0);                                        \
      }                                                                       \
    }                                                                         \
  }

  int4 kA0, kA1, vA0, vA1, kB0, kB1, vB0, vB1;
  int mA = 0, mB = 0;
  PREFETCH_KV(kt0, kA0, kA1, vA0, vA1, mA);

  for (int i = 0; i < 4; ++i) {
    const int base = kt0 + i * 2;
    if (i) __syncthreads();                 // prev tile's LDS reads done
    PREFETCH_KV(base + 1, kB0, kB1, vB0, vB1, mB);   // in flight over tile A
    STORE_KV(kA0, kA1, vA0, vA1, mA);
    __syncthreads();
    COMPUTE_TILE();
    __syncthreads();                        // tile A's LDS reads done
    if (i < 3) PREFETCH_KV(base + 2, kA0, kA1, vA0, vA1, mA);  // over tile B
    STORE_KV(kB0, kB1, vB0, vB1, mB);
    __syncthreads();
    COMPUTE_TILE();
  }

#undef PREFETCH_KV
#undef STORE_KV
#undef COMPUTE_TILE

  // ---- l partials: 16-lane group reduce, plain store ----
  #pragma unroll
  for (int m = 1; m < 16; m <<= 1) {
    #pragma unroll
    for (int g = 0; g < 2; ++g)
      #pragma unroll
      for (int r = 0; r < 4; ++r) rs[g][r] += __shfl_xor(rs[g][r], m);
  }
  if (ln == 0) {
    #pragma unroll
    for (int g = 0; g < 2; ++g) {
      float* lp = lws + (size_t)quarter * kNL + ((size_t)b * kH + h) * kS +
                  q0 + w * 32 + g * 16 + quad * 4;
      #pragma unroll
      for (int r = 0; r < 4; ++r) lp[r] = rs[g][r];
    }
  }

  // ---- O partials: RNE bf16, LDS repack, coalesced stores ----
  __syncthreads();   // Kh/Vh dead
  #pragma unroll
  for (int g = 0; g < 2; ++g)
    #pragma unroll
    for (int db = 0; db < 4; ++db)
      #pragma unroll
      for (int r = 0; r < 4; ++r)
        QT[w * 32 + g * 16 + quad * 4 + r][db * 16 + ln] = rne_bf16(O[g][db][r]);
  __syncthreads();
  ushort_t* op = Opart + (size_t)quarter * kNE;
  #pragma unroll
  for (int cc = 0; cc < 4; ++cc) {
    const int id = tid + cc * 256;
    const int r = id >> 3, c = id & 7;
    *(int4*)&op[((size_t)b * kS + q0 + r) * kDM + h * kD + c * 8] = *(int4*)&QT[r][c * 8];
  }
}

// ---------------------------------------------------------------------------
// Kernel 3: MFMA output projection with fused split-K combine.
// This round: k-step 32 -> 64 (8 iterations instead of 16; barrier count
// halved). At k-step 64 each iteration spans exactly one head (hh = k0>>6).
// LDS ~47 KB (fits 2 blocks/CU at (256,2)); prefetch 12 x int4 = 48 VGPR
// against the 256-reg cap — ample margin, no spill risk.
// grid (B*S/32, DM/128), block 256 (4 waves: tsub = w&1, esub = w>>1).
// ---------------------------------------------------------------------------
__global__ __launch_bounds__(256, 2)
void out_proj_kernel(const ushort_t* __restrict__ Opart, const float* __restrict__ lws,
                     const ushort_t* __restrict__ wh, const ushort_t* __restrict__ wl,
                     const float* __restrict__ bo, float* __restrict__ out) {
  __shared__ __align__(16) ushort_t Ah[32][72];
  __shared__ __align__(16) ushort_t Al[32][72];
  __shared__ __align__(16) ushort_t Bh[128][72];
  __shared__ __align__(16) ushort_t Bl[128][72];
  __shared__ float linv[kH][32];
  const int t0 = blockIdx.x * 32;
  const int e0 = blockIdx.y * 128;
  const int b  = t0 >> 11;
  const int s0 = t0 & (kS - 1);
  const int tid  = threadIdx.x;
  const int w    = tid >> 6;
  const int lane = tid & 63;
  const int ln   = lane & 15;
  const int quad = lane >> 4;
  const int tsub = w & 1;
  const int esub = w >> 1;

  {  // 8 heads x 32 rows: one l-sum per thread
    const int hh = tid >> 5, r = tid & 31;
    const size_t base = ((size_t)b * kH + hh) * kS + s0 + r;
    linv[hh][r] = 1.0f / (lws[base] + lws[kNL + base] +
                          lws[2 * kNL + base] + lws[3 * kNL + base]);
  }

  // per-thread staging coordinates (constant across the k-loop)
  const int ra = tid >> 3, ca = (tid & 7) * 8;   // A: 32 rows x 64 cols, 8/thr
  const int rb = tid >> 3, cb = (tid & 7) * 8;   // B: rows 0..31 (+32/64/96)
  const ushort_t* ap  = &Opart[(size_t)(t0 + ra) * kDM + ca];
  const ushort_t* bhp = &wh[(size_t)(e0 + rb) * kDM + cb];
  const ushort_t* blp = &wl[(size_t)(e0 + rb) * kDM + cb];

  f32x4 C[4];
  #pragma unroll
  for (int eb = 0; eb < 4; ++eb) C[eb] = (f32x4){0.f, 0.f, 0.f, 0.f};

  // ---- prefetch k0 = 0 (A: 4 quarters x int4; B: 4 row-chunks x h,l) ----
  int4 pa0 = *(const int4*)(ap);
  int4 pa1 = *(const int4*)(ap + kNE);
  int4 pa2 = *(const int4*)(ap + 2 * kNE);
  int4 pa3 = *(const int4*)(ap + 3 * kNE);
  int4 ph0 = *(const int4*)(bhp);
  int4 ph1 = *(const int4*)(bhp + (size_t)32 * kDM);
  int4 ph2 = *(const int4*)(bhp + (size_t)64 * kDM);
  int4 ph3 = *(const int4*)(bhp + (size_t)96 * kDM);
  int4 pl0 = *(const int4*)(blp);
  int4 pl1 = *(const int4*)(blp + (size_t)32 * kDM);
  int4 pl2 = *(const int4*)(blp + (size_t)64 * kDM);
  int4 pl3 = *(const int4*)(blp + (size_t)96 * kDM);

  for (int k0 = 0; k0 < kDM; k0 += 64) {
    __syncthreads();
    // ---- consume prefetched A: 8 elems, sum 4 partials -> /l -> split ----
    {
      const float li = linv[k0 >> 6][ra];
      float a0 = bf_to_f((unsigned)pa0.x & 0xffffu) + bf_to_f((unsigned)pa1.x & 0xffffu) +
                 bf_to_f((unsigned)pa2.x & 0xffffu) + bf_to_f((unsigned)pa3.x & 0xffffu);
      float a1 = bf_to_f((unsigned)pa0.x >> 16) + bf_to_f((unsigned)pa1.x >> 16) +
                 bf_to_f((unsigned)pa2.x >> 16) + bf_to_f((unsigned)pa3.x >> 16);
      float a2 = bf_to_f((unsigned)pa0.y & 0xffffu) + bf_to_f((unsigned)pa1.y & 0xffffu) +
                 bf_to_f((unsigned)pa2.y & 0xffffu) + bf_to_f((unsigned)pa3.y & 0xffffu);
      float a3 = bf_to_f((unsigned)pa0.y >> 16) + bf_to_f((unsigned)pa1.y >> 16) +
                 bf_to_f((unsigned)pa2.y >> 16) + bf_to_f((unsigned)pa3.y >> 16);
      float a4 = bf_to_f((unsigned)pa0.z & 0xffffu) + bf_to_f((unsigned)pa1.z & 0xffffu) +
                 bf_to_f((unsigned)pa2.z & 0xffffu) + bf_to_f((unsigned)pa3.z & 0xffffu);
      float a5 = bf_to_f((unsigned)pa0.z >> 16) + bf_to_f((unsigned)pa1.z >> 16) +
                 bf_to_f((unsigned)pa2.z >> 16) + bf_to_f((unsigned)pa3.z >> 16);
      float a6 = bf_to_f((unsigned)pa0.w & 0xffffu) + bf_to_f((unsigned)pa1.w & 0xffffu) +
                 bf_to_f((unsigned)pa2.w & 0xffffu) + bf_to_f((unsigned)pa3.w & 0xffffu);
      float a7 = bf_to_f((unsigned)pa0.w >> 16) + bf_to_f((unsigned)pa1.w >> 16) +
                 bf_to_f((unsigned)pa2.w >> 16) + bf_to_f((unsigned)pa3.w >> 16);
      a0 *= li; a1 *= li; a2 *= li; a3 *= li;
      a4 *= li; a5 *= li; a6 *= li; a7 *= li;
      ushort_t h8[8], l8[8];
      split_bf16(a0, h8[0], l8[0]);
      split_bf16(a1, h8[1], l8[1]);
      split_bf16(a2, h8[2], l8[2]);
      split_bf16(a3, h8[3], l8[3]);
      split_bf16(a4, h8[4], l8[4]);
      split_bf16(a5, h8[5], l8[5]);
      split_bf16(a6, h8[6], l8[6]);
      split_bf16(a7, h8[7], l8[7]);
      int4 hp, lp;
      hp.x = (int)((unsigned)h8[0] | ((unsigned)h8[1] << 16));
      hp.y = (int)((unsigned)h8[2] | ((unsigned)h8[3] << 16));
      hp.z = (int)((unsigned)h8[4] | ((unsigned)h8[5] << 16));
      hp.w = (int)((unsigned)h8[6] | ((unsigned)h8[7] << 16));
      lp.x = (int)((unsigned)l8[0] | ((unsigned)l8[1] << 16));
      lp.y = (int)((unsigned)l8[2] | ((unsigned)l8[3] << 16));
      lp.z = (int)((unsigned)l8[4] | ((unsigned)l8[5] << 16));
      lp.w = (int)((unsigned)l8[6] | ((unsigned)l8[7] << 16));
      *(int4*)&Ah[ra][ca] = hp;
      *(int4*)&Al[ra][ca] = lp;
    }
    // ---- consume prefetched B ----
    *(int4*)&Bh[rb][cb]      = ph0;
    *(int4*)&Bh[rb + 32][cb] = ph1;
    *(int4*)&Bh[rb + 64][cb] = ph2;
    *(int4*)&Bh[rb + 96][cb] = ph3;
    *(int4*)&Bl[rb][cb]      = pl0;
    *(int4*)&Bl[rb + 32][cb] = pl1;
    *(int4*)&Bl[rb + 64][cb] = pl2;
    *(int4*)&Bl[rb + 96][cb] = pl3;
    // ---- issue next iteration's loads (latency hides under MFMA) ----
    if (k0 + 64 < kDM) {
      const int kn = k0 + 64;
      pa0 = *(const int4*)(ap + kn);
      pa1 = *(const int4*)(ap + kNE + kn);
      pa2 = *(const int4*)(ap + 2 * kNE + kn);
      pa3 = *(const int4*)(ap + 3 * kNE + kn);
      ph0 = *(const int4*)(bhp + kn);
      ph1 = *(const int4*)(bhp + (size_t)32 * kDM + kn);
      ph2 = *(const int4*)(bhp + (size_t)64 * kDM + kn);
      ph3 = *(const int4*)(bhp + (size_t)96 * kDM + kn);
      pl0 = *(const int4*)(blp + kn);
      pl1 = *(const int4*)(blp + (size_t)32 * kDM + kn);
      pl2 = *(const int4*)(blp + (size_t)64 * kDM + kn);
      pl3 = *(const int4*)(blp + (size_t)96 * kDM + kn);
    }
    __syncthreads();
    #pragma unroll
    for (int kc = 0; kc < 2; ++kc) {
      const s16x8 ah = *(const s16x8*)&Ah[tsub * 16 + ln][kc * 32 + quad * 8];
      const s16x8 al = *(const s16x8*)&Al[tsub * 16 + ln][kc * 32 + quad * 8];
      #pragma unroll
      for (int eb = 0; eb < 4; ++eb) {
        const s16x8 bh = *(const s16x8*)&Bh[esub * 64 + eb * 16 + ln][kc * 32 + quad * 8];
        const s16x8 bl = *(const s16x8*)&Bl[esub * 64 + eb * 16 + ln][kc * 32 + quad * 8];
        C[eb] = __builtin_amdgcn_mfma_f32_16x16x32_bf16(ah, bh, C[eb], 0, 0, 0);
        C[eb] = __builtin_amdgcn_mfma_f32_16x16x32_bf16(ah, bl, C[eb], 0, 0, 0);
        C[eb] = __builtin_amdgcn_mfma_f32_16x16x32_bf16(al, bh, C[eb], 0, 0, 0);
      }
    }
  }

  #pragma unroll
  for (int eb = 0; eb < 4; ++eb) {
    const int e = e0 + esub * 64 + eb * 16 + ln;
    const float be = bo[e];
    #pragma unroll
    for (int r = 0; r < 4; ++r) {
      const int t = t0 + tsub * 16 + quad * 4 + r;
      out[(size_t)t * kDM + e] = C[eb][r] + be;
    }
  }
}

// ---------------------------------------------------------------------------
extern "C" void kernel_launch(void* const* d_in, const int* in_sizes, int n_in,
                              void* d_out, int out_size, void* d_ws, size_t ws_size,
                              hipStream_t stream) {
  const float* query = (const float*)d_in[0];
  const float* key   = (const float*)d_in[1];
  const float* value = (const float*)d_in[2];
  const float* Wq = (const float*)d_in[3];
  const float* bq = (const float*)d_in[4];
  const float* Wk = (const float*)d_in[5];
  const float* bk = (const float*)d_in[6];
  const float* Wv = (const float*)d_in[7];
  const float* bv = (const float*)d_in[8];
  const float* Wo = (const float*)d_in[9];
  const float* bo = (const float*)d_in[10];
  const int* mask = (const int*)d_in[11];
  float* out = (float*)d_out;

  ushort_t* k_hi  = (ushort_t*)d_ws;            // 4MB
  ushort_t* vt_hi = k_hi + kNE;                 // 4MB
  ushort_t* wo_h  = vt_hi + kNE;                // 512KB
  ushort_t* wo_l  = wo_h + (size_t)kDM * kDM;   // 512KB
  ushort_t* Opart = wo_l + (size_t)kDM * kDM;   // 16MB (4 quarters, bf16)
  float*    lws   = (float*)(Opart + 4 * kNE);  // 512KB (4 quarters)
  ushort_t* q_hi  = (ushort_t*)(lws + 4 * kNL); // 4MB   (total ~29.5 MB)

  proj_kernel<<<dim3(kB * kS / 64, kH, 4), 256, 0, stream>>>(
      key, value, query, Wk, bk, Wv, bv, Wq, bq, Wo, wo_h, wo_l, k_hi, vt_hi, q_hi);
  attn_kernel<<<dim3(kS / 128, kH, kB * 4), 256, 0, stream>>>(
      q_hi, k_hi, vt_hi, mask, Opart, lws);
  out_proj_kernel<<<dim3(kB * kS / 32, kDM / 128), 256, 0, stream>>>(
      Opart, lws, wo_h, wo_l, bo, out);
}